// Round 5
// baseline (488.604 us; speedup 1.0000x reference)
//
#include <hip/hip_runtime.h>
#include <math.h>

// Problem constants
#define BATCH 128
#define NPER 400
#define EPG 6400
#define NEDGE 819200
#define F_IN 400
#define HD 128
#define K1 320
#define K2 256
#define K3 205

typedef __bf16 bf16x8 __attribute__((ext_vector_type(8)));
typedef float f32x4 __attribute__((ext_vector_type(4)));

__device__ __forceinline__ unsigned short f2bf(float f) {
    unsigned u = __builtin_bit_cast(unsigned, f);
    unsigned r = u + 0x7fffu + ((u >> 16) & 1u);
    return (unsigned short)(r >> 16);
}
__device__ __forceinline__ float bf2f(unsigned short s) {
    unsigned u = ((unsigned)s) << 16;
    return __builtin_bit_cast(float, u);
}

// async global -> LDS copy, 16 bytes per lane (global_load_lds_dwordx4).
// LDS dest is wave-uniform base + lane*16 (HW behavior); global src is per-lane.
__device__ __forceinline__ void async_ld16(const void* g, void* lds) {
    __builtin_amdgcn_global_load_lds(
        (const __attribute__((address_space(1))) unsigned int*)g,
        (__attribute__((address_space(3))) unsigned int*)lds, 16, 0, 0);
}

// ---------------- workspace layout ----------------
static constexpr size_t SZ_TREL = 51200ull * 128 * 4;
static constexpr size_t OFF_TREL = 0;
static constexpr size_t OFF_H    = OFF_TREL + SZ_TREL;
static constexpr size_t OFF_HP   = OFF_H + SZ_TREL;
static constexpr size_t OFF_SC   = OFF_HP + 40960ull * 128 * 4;
static constexpr size_t OFF_ES   = OFF_SC + 51200ull * 4;
static constexpr size_t OFF_ED   = OFF_ES + (size_t)NEDGE * 4;
static constexpr size_t OFF_EM   = OFF_ED + (size_t)NEDGE * 4;
static constexpr size_t OFF_Z    = OFF_EM + (size_t)NEDGE * 4;
static constexpr size_t OFF_COFF = OFF_Z + 128ull * 256 * 4;
static constexpr size_t OFF_CDEG = OFF_COFF + 51200ull * 4;
static constexpr size_t OFF_CSRC = OFF_CDEG + 51200ull * 4;
static constexpr size_t OFF_W1H  = OFF_CSRC + (size_t)NEDGE * 4;   // 16*13*512 shorts
static constexpr size_t OFF_W1L  = OFF_W1H + 16ull * 13 * 512 * 2;
static constexpr size_t OFF_W2H  = OFF_W1L + 16ull * 13 * 512 * 2;
static constexpr size_t OFF_W2L  = OFF_W2H + 16ull * 4 * 512 * 2;
static constexpr size_t OFF_W3H  = OFF_W2L + 16ull * 4 * 512 * 2;
static constexpr size_t OFF_W3L  = OFF_W3H + 16ull * 4 * 512 * 2;

// ---------------- weight split + fragment-tile prep (all 3 layers) ---------
// chunk[(n_tile*Ks + s)*512 + lane*8 + e] = B[n_tile*16 + (lane&15)][s*32 + (lane>>4)*8 + e]
__global__ __launch_bounds__(64) void prep_w_all(
    const float* __restrict__ Wrel1, const float* __restrict__ Wroot1,
    const float* __restrict__ Wrel2, const float* __restrict__ Wroot2,
    const float* __restrict__ Wrel3, const float* __restrict__ Wroot3,
    unsigned short* __restrict__ b1h, unsigned short* __restrict__ b1l,
    unsigned short* __restrict__ b2h, unsigned short* __restrict__ b2l,
    unsigned short* __restrict__ b3h, unsigned short* __restrict__ b3l) {
    const int layer = blockIdx.z;
    const int s = blockIdx.x;
    const int ntile = blockIdx.y;
    const int Ks = (layer == 0) ? 13 : 4;
    const int Kd = (layer == 0) ? F_IN : HD;
    if (s >= Ks) return;
    const float* Wrel  = (layer == 0) ? Wrel1  : (layer == 1) ? Wrel2  : Wrel3;
    const float* Wroot = (layer == 0) ? Wroot1 : (layer == 1) ? Wroot2 : Wroot3;
    unsigned short* bh = (layer == 0) ? b1h : (layer == 1) ? b2h : b3h;
    unsigned short* bl = (layer == 0) ? b1l : (layer == 1) ? b2l : b3l;
    const int t = threadIdx.x;
    const int rowin = t & 15, qd = t >> 4;
    const int n = ntile * 16 + rowin;
    const int k = s * 32 + qd * 8;
    const float* src = (n < 128) ? &Wrel[(n & 127) * Kd] : &Wroot[(n & 127) * Kd];
    unsigned short hv[8], lv[8];
#pragma unroll
    for (int e = 0; e < 8; e++) {
        float f = (k + e < Kd) ? src[k + e] : 0.f;
        unsigned short hi = f2bf(f);
        hv[e] = hi;
        lv[e] = f2bf(f - bf2f(hi));
    }
    size_t o = ((size_t)ntile * Ks + s) * 512 + (size_t)t * 8;
#pragma unroll
    for (int e = 0; e < 8; e++) { bh[o + e] = hv[e]; bl[o + e] = lv[e]; }
}

// ---------------- MFMA GEMM: fully wave-independent, ZERO barriers ---------
// Each wave owns a 32-row x 64-col output tile: block b, wave w -> rows
// blockIdx.x*32, cols w*64. Each wave stages its OWN 32x32-f32 A-chunk into
// PRIVATE LDS via global_load_lds (double-buffered, depth-1 prefetch) and
// syncs only on its own per-wave vmcnt counter -- no s_barrier anywhere.
// 4 blocks/CU (32KB LDS, ~<=112 unified regs) = 16 independent wave pipelines
// per CU; TLP hides A/B load latency and ds_read latency.
// LDS layout per wave-buffer: row-major [32 rows][8 granules of 16B], XOR-
// swizzled: slot g holds data granule g^(row&7). Swizzle applied on the
// GLOBAL SOURCE address (DMA writes linearly) and on the ds_read offset.
template <int Ks, int Kd>
__global__ __launch_bounds__(256, 4) void gemm_wave(
    const float* __restrict__ A,
    const unsigned short* __restrict__ bh_p, const unsigned short* __restrict__ bl_p,
    float* __restrict__ t_rel, float* __restrict__ h) {
    __shared__ float Alds[4][2][1024];   // [wave][buf][32x32 f32] = 32KB
    const int tid = threadIdx.x;
    const int lane = tid & 63;
    const int wv = tid >> 6;            // = col-tile group 0..3
    const int lm = lane & 15;
    const int qd = (lane >> 4) & 3;
    const int m0 = blockIdx.x * 32;
    const int nt0 = wv * 4;

    // ---- staging geometry: inst q writes rows q*8+ (lane>>3), slot lane&7 ----
    const int srow = lane >> 3;                 // row&7 for this lane
    const int sgr  = (lane & 7) ^ srow;         // data granule to fetch (pre-swizzle)
    const size_t amax = (size_t)gridDim.x * 32 * Kd * 4 - 16;  // K-tail clamp
    const char* Abyte = (const char*)A;

    // ---- compute-side swizzled LDS byte offsets ----
    const int ga = (((2 * qd)     ^ (lm & 7)) << 4);
    const int gb = (((2 * qd + 1) ^ (lm & 7)) << 4);

    f32x4 acc[2][4];
#pragma unroll
    for (int i = 0; i < 2; i++)
#pragma unroll
        for (int j = 0; j < 4; j++) acc[i][j] = (f32x4){0.f, 0.f, 0.f, 0.f};

    auto stage = [&](int buf, int s) {
#pragma unroll
        for (int q = 0; q < 4; ++q) {
            size_t go = (size_t)(m0 + q * 8 + srow) * Kd * 4 + (size_t)s * 128
                        + ((size_t)sgr << 4);
            if (go > amax) go = amax;   // K-tail: garbage fetched, zeroed on read
            async_ld16(Abyte + go, &Alds[wv][buf][q * 256]);
        }
    };

    stage(0, 0);   // prologue: tile 0 DMA in flight

#pragma unroll
    for (int s = 0; s < Ks; ++s) {
        // ---- B fragment loads for this step (issued before next-stage DMA) --
        bf16x8 bhc[4], blc[4];
#pragma unroll
        for (int j = 0; j < 4; j++)
            bhc[j] = *(const bf16x8*)&bh_p[((size_t)(nt0 + j) * Ks + s) * 512 + lane * 8];
#pragma unroll
        for (int j = 0; j < 4; j++)
            blc[j] = *(const bf16x8*)&bl_p[((size_t)(nt0 + j) * Ks + s) * 512 + lane * 8];
        // ---- next tile's DMA (per-wave, private buffer) ----
        if (s + 1 < Ks) stage((s + 1) & 1, s + 1);

        // ---- per-wave counted wait: retire stage(s) DMA only.
        // outstanding newer than stage(s): B(s) x8 [+ stage(s+1) x4]
        if (s + 1 < Ks) asm volatile("s_waitcnt vmcnt(12)" ::: "memory");
        else            asm volatile("s_waitcnt vmcnt(8)" ::: "memory");

        // ---- A: swizzled ds_read + in-register hi/lo split ----
        const char* Ab = (const char*)&Alds[wv][s & 1][0];
        bf16x8 ah[2], al[2];
#pragma unroll
        for (int i = 0; i < 2; i++) {
            f32x4 f0, f1;
            if (s * 32 + qd * 8 < Kd) {
                const char* base = Ab + (lm + i * 16) * 128;
                f0 = *(const f32x4*)(base + ga);
                f1 = *(const f32x4*)(base + gb);
            } else {
                f0 = (f32x4){0.f, 0.f, 0.f, 0.f};
                f1 = f0;
            }
            float fe[8] = {f0[0], f0[1], f0[2], f0[3], f1[0], f1[1], f1[2], f1[3]};
#pragma unroll
            for (int e = 0; e < 8; e++) {
                __bf16 hb = (__bf16)fe[e];
                ah[i][e] = hb;
                al[i][e] = (__bf16)(fe[e] - (float)hb);
            }
        }
        // ---- MFMA: hi*hi + lo*hi + hi*lo (per-acc order preserved) ----
        __builtin_amdgcn_s_setprio(1);
#pragma unroll
        for (int j = 0; j < 4; j++)
#pragma unroll
            for (int i = 0; i < 2; i++)
                acc[i][j] = __builtin_amdgcn_mfma_f32_16x16x32_bf16(
                    ah[i], bhc[j], acc[i][j], 0, 0, 0);
#pragma unroll
        for (int j = 0; j < 4; j++)
#pragma unroll
            for (int i = 0; i < 2; i++)
                acc[i][j] = __builtin_amdgcn_mfma_f32_16x16x32_bf16(
                    al[i], bhc[j], acc[i][j], 0, 0, 0);
#pragma unroll
        for (int j = 0; j < 4; j++)
#pragma unroll
            for (int i = 0; i < 2; i++)
                acc[i][j] = __builtin_amdgcn_mfma_f32_16x16x32_bf16(
                    ah[i], blc[j], acc[i][j], 0, 0, 0);
        __builtin_amdgcn_s_setprio(0);
    }
    // ---- epilogue: C/D layout col=lane&15, row=qd*4+reg ----
    float* out = (wv < 2) ? t_rel : h;
    const int colbase = (wv & 1) * 64;
#pragma unroll
    for (int i = 0; i < 2; i++)
#pragma unroll
        for (int j = 0; j < 4; j++) {
            int row = m0 + i * 16 + qd * 4;
            int col = colbase + j * 16 + lm;
#pragma unroll
            for (int r = 0; r < 4; r++)
                out[(size_t)(row + r) * 128 + col] = acc[i][j][r];
        }
}

// ---------------- CSR build for layer 1 (original edges, no mask) ----------
__global__ __launch_bounds__(1024) void csr_build0(
    const int* __restrict__ gsrc, const int* __restrict__ gdst,
    int* __restrict__ csr_off, int* __restrict__ csr_deg, int* __restrict__ csr_src) {
    __shared__ int cnt[NPER];
    __shared__ int cur[NPER];
    __shared__ int sscan[512];
    const int g = blockIdx.x;
    const int t = threadIdx.x;
    for (int i = t; i < NPER; i += 1024) cnt[i] = 0;
    __syncthreads();
    for (int e = t; e < EPG; e += 1024) {
        int dl = gdst[g * EPG + e] - g * NPER;
        atomicAdd(&cnt[dl], 1);
    }
    __syncthreads();
    if (t < 512) sscan[t] = (t < NPER) ? cnt[t] : 0;
    __syncthreads();
    for (int d = 1; d < 512; d <<= 1) {
        int v = 0;
        if (t < 512 && t >= d) v = sscan[t - d];
        __syncthreads();
        if (t < 512 && t >= d) sscan[t] += v;
        __syncthreads();
    }
    if (t < NPER) {
        int excl = (t == 0) ? 0 : sscan[t - 1];
        int st = g * EPG + excl;
        csr_off[g * NPER + t] = st;
        csr_deg[g * NPER + t] = cnt[t];
        cur[t] = st;
    }
    __syncthreads();
    for (int e = t; e < EPG; e += 1024) {
        int eg = g * EPG + e;
        int dl = gdst[eg] - g * NPER;
        int slot = atomicAdd(&cur[dl], 1);
        csr_src[slot] = gsrc[eg];
    }
}

// ---------------- Aggregation (gather) + combine + relu + score ------------
__global__ __launch_bounds__(256) void agg_score(
    const float* __restrict__ t_rel,
    const int* __restrict__ csr_off, const int* __restrict__ csr_deg,
    const int* __restrict__ csr_src,
    const float* __restrict__ bias, const float* __restrict__ pw,
    float* __restrict__ h, float* __restrict__ sc, int npg) {
    const int xcd = blockIdx.x & 7;
    const int j = blockIdx.x >> 3;
    const int bpg = npg >> 2;
    const int graph = xcd * (BATCH / 8) + j / bpg;
    const int nblk = j - (j / bpg) * bpg;
    const int wid = graph * npg + nblk * 4 + (threadIdx.x >> 6);
    const int lane = threadIdx.x & 63;

    const int start = csr_off[wid];
    const int deg = csr_deg[wid];
    const size_t fo = (size_t)lane * 2;
    float a0 = 0.f, a1 = 0.f, b0 = 0.f, b1 = 0.f;
    float c0 = 0.f, c1 = 0.f, d0 = 0.f, d1 = 0.f;
    int e = 0;
    for (; e + 4 <= deg; e += 4) {
        int s0 = csr_src[start + e];
        int s1 = csr_src[start + e + 1];
        int s2 = csr_src[start + e + 2];
        int s3 = csr_src[start + e + 3];
        float2 v0 = *(const float2*)&t_rel[(size_t)s0 * 128 + fo];
        float2 v1 = *(const float2*)&t_rel[(size_t)s1 * 128 + fo];
        float2 v2 = *(const float2*)&t_rel[(size_t)s2 * 128 + fo];
        float2 v3 = *(const float2*)&t_rel[(size_t)s3 * 128 + fo];
        a0 += v0.x; a1 += v0.y;
        b0 += v1.x; b1 += v1.y;
        c0 += v2.x; c1 += v2.y;
        d0 += v3.x; d1 += v3.y;
    }
    for (; e < deg; e++) {
        int s0 = csr_src[start + e];
        float2 v0 = *(const float2*)&t_rel[(size_t)s0 * 128 + fo];
        a0 += v0.x; a1 += v0.y;
    }
    a0 += b0 + c0 + d0;
    a1 += b1 + c1 + d1;

    float2 bb = *(const float2*)&bias[fo];
    size_t o = (size_t)wid * 128 + fo;
    float2 hv = *(const float2*)&h[o];
    hv.x = fmaxf(hv.x + a0 + bb.x, 0.f);
    hv.y = fmaxf(hv.y + a1 + bb.y, 0.f);
    *(float2*)&h[o] = hv;
    float2 pp = *(const float2*)&pw[fo];
    float d = hv.x * pp.x + hv.y * pp.y;
    float nr = pp.x * pp.x + pp.y * pp.y;
#pragma unroll
    for (int off = 32; off; off >>= 1) {
        d += __shfl_down(d, off, 64);
        nr += __shfl_down(nr, off, 64);
    }
    if (lane == 0) sc[wid] = d / (sqrtf(nr) + 1e-16f);
}

// ---------------- fused topk + pool/readout + edge-remap/CSR ---------------
// One block per graph, 1024 threads. mode: 0=L1 (edges from gsrc/gdst),
// 1=L2 (edges from es/ed/em in-place), 2=L3 (no remap, no hp write).
__device__ __forceinline__ bool rank_before(float as, int ai, float bs, int bi) {
    return (as > bs) || (as == bs && ai < bi);
}
__global__ __launch_bounds__(1024) void topk_pool(
    const float* __restrict__ sc, const float* __restrict__ h,
    float* __restrict__ hp, float* __restrict__ z,
    const int* __restrict__ gsrc, const int* __restrict__ gdst,
    int* __restrict__ es, int* __restrict__ ed, int* __restrict__ em,
    int* __restrict__ csr_off, int* __restrict__ csr_deg, int* __restrict__ csr_src,
    int npg, int k, int mode) {
    __shared__ float sk[512];
    __shared__ int si[512];
    __shared__ int nid[NPER];
    __shared__ float tgs[K1];
    __shared__ int packed[EPG];
    __shared__ int cnt[K1];
    __shared__ int cur[K1];
    __shared__ int sscan[512];
    __shared__ float pmx[8][128], psm[8][128];
    const int g = blockIdx.x;
    const int t = threadIdx.x;

    // ---- phase 1: sort scores (desc, index tiebreak) ----
    if (t < 512) {
        sk[t] = (t < npg) ? sc[g * npg + t] : -INFINITY;
        si[t] = t;
    }
    __syncthreads();
    for (int size = 2; size <= 512; size <<= 1) {
        for (int stride = size >> 1; stride; stride >>= 1) {
            if (t < 512) {
                int i = t, j = i ^ stride;
                if (j > i) {
                    bool up = ((i & size) == 0);
                    float a = sk[i], b = sk[j];
                    int ai = si[i], bi = si[j];
                    bool doswap = up ? rank_before(b, bi, a, ai)
                                     : rank_before(a, ai, b, bi);
                    if (doswap) { sk[i] = b; sk[j] = a; si[i] = bi; si[j] = ai; }
                }
            }
            __syncthreads();
        }
    }
    // ---- phase 2: newid + tanh gates ----
    if (t < 512) {
        int orig = si[t];
        if (orig < npg) nid[orig] = (t < k) ? t : -1;
        if (t < k) tgs[t] = tanhf(sk[t]);
    }
    if (t < K1) cnt[t] = 0;
    __syncthreads();

    // ---- phase 3: pool + readout (+hp for next layer) ----
    {
        const int f = t & 127;
        const int jq = t >> 7;     // 0..7
        float mx = -INFINITY, sm = 0.f;
        for (int j = jq; j < k; j += 8) {
            float v = h[(size_t)(g * npg + si[j]) * 128 + f] * tgs[j];
            if (mode != 2) hp[(size_t)(g * k + j) * 128 + f] = v;
            mx = fmaxf(mx, v);
            sm += v;
        }
        pmx[jq][f] = mx; psm[jq][f] = sm;
        __syncthreads();
        if (t < 128) {
            mx = pmx[0][t]; sm = psm[0][t];
#pragma unroll
            for (int q = 1; q < 8; q++) {
                mx = fmaxf(mx, pmx[q][t]);
                sm += psm[q][t];
            }
            z[g * 256 + t] += mx;
            z[g * 256 + 128 + t] += sm / (float)k;
        }
    }
    if (mode == 2) return;

    // ---- phase 4: edge remap + CSR build over pooled node space ----
    for (int e = t; e < EPG; e += 1024) {
        int eg = g * EPG + e;
        int sl, dl, m;
        if (mode == 0) { sl = gsrc[eg] - g * NPER; dl = gdst[eg] - g * NPER; m = 1; }
        else           { sl = es[eg]; dl = ed[eg]; m = em[eg]; }
        int ns = nid[sl], nd = nid[dl];
        int keep = (m && ns >= 0 && nd >= 0) ? 1 : 0;
        es[eg] = keep ? ns : 0;
        ed[eg] = keep ? nd : 0;
        em[eg] = keep;
        packed[e] = keep ? (ns | (nd << 16)) : -1;
        if (keep) atomicAdd(&cnt[nd], 1);
    }
    __syncthreads();
    if (t < 512) sscan[t] = (t < k) ? cnt[t] : 0;
    __syncthreads();
    for (int d = 1; d < 512; d <<= 1) {
        int v = 0;
        if (t < 512 && t >= d) v = sscan[t - d];
        __syncthreads();
        if (t < 512 && t >= d) sscan[t] += v;
        __syncthreads();
    }
    if (t < k) {
        int excl = (t == 0) ? 0 : sscan[t - 1];
        int st = g * EPG + excl;
        csr_off[g * k + t] = st;
        csr_deg[g * k + t] = cnt[t];
        cur[t] = st;
    }
    __syncthreads();
    for (int e = t; e < EPG; e += 1024) {
        int p = packed[e];
        if (p >= 0) {
            int ns = p & 0xffff, nd = p >> 16;
            int slot = atomicAdd(&cur[nd], 1);
            csr_src[slot] = g * k + ns;
        }
    }
}

// ---------------- MLP head + log_softmax ----------------
__global__ __launch_bounds__(256) void mlp_head(const float* __restrict__ z,
                                                const float* __restrict__ W1,
                                                const float* __restrict__ bl1,
                                                const float* __restrict__ W2,
                                                const float* __restrict__ bl2,
                                                const float* __restrict__ W3,
                                                const float* __restrict__ bl3,
                                                float* __restrict__ out) {
    __shared__ float zs[256], l1[128], l2[64];
    const int g = blockIdx.x, t = threadIdx.x;
    zs[t] = z[g * 256 + t];
    __syncthreads();
    if (t < 128) {
        float s = bl1[t];
        const float* w = &W1[t * 256];
        for (int i = 0; i < 256; i++) s += w[i] * zs[i];
        l1[t] = fmaxf(s, 0.f);
    }
    __syncthreads();
    if (t < 64) {
        float s = bl2[t];
        const float* w = &W2[t * 128];
        for (int i = 0; i < 128; i++) s += w[i] * l1[i];
        l2[t] = fmaxf(s, 0.f);
    }
    __syncthreads();
    if (t == 0) {
        float a = bl3[0], b = bl3[1];
        for (int i = 0; i < 64; i++) { a += W3[i] * l2[i]; b += W3[64 + i] * l2[i]; }
        float m = fmaxf(a, b);
        float lse = m + logf(expf(a - m) + expf(b - m));
        out[g * 2 + 0] = a - lse;
        out[g * 2 + 1] = b - lse;
    }
}

// ---------------- launch ----------------
extern "C" void kernel_launch(void* const* d_in, const int* in_sizes, int n_in,
                              void* d_out, int out_size, void* d_ws, size_t ws_size,
                              hipStream_t stream) {
    const float* x        = (const float*)d_in[0];
    const int*   edge_src = (const int*)d_in[1];
    const int*   edge_dst = (const int*)d_in[2];
    const float* Wrel1 = (const float*)d_in[4];
    const float* Wroot1= (const float*)d_in[5];
    const float* b1    = (const float*)d_in[6];
    const float* pw1   = (const float*)d_in[7];
    const float* Wrel2 = (const float*)d_in[8];
    const float* Wroot2= (const float*)d_in[9];
    const float* b2    = (const float*)d_in[10];
    const float* pw2   = (const float*)d_in[11];
    const float* Wrel3 = (const float*)d_in[12];
    const float* Wroot3= (const float*)d_in[13];
    const float* b3    = (const float*)d_in[14];
    const float* pw3   = (const float*)d_in[15];
    const float* W1    = (const float*)d_in[16];
    const float* bl1   = (const float*)d_in[17];
    const float* W2    = (const float*)d_in[18];
    const float* bl2   = (const float*)d_in[19];
    const float* W3    = (const float*)d_in[20];
    const float* bl3   = (const float*)d_in[21];

    char* ws = (char*)d_ws;
    float* t_rel = (float*)(ws + OFF_TREL);
    float* h     = (float*)(ws + OFF_H);
    float* hp    = (float*)(ws + OFF_HP);
    float* sc    = (float*)(ws + OFF_SC);
    int*   es    = (int*)(ws + OFF_ES);
    int*   ed    = (int*)(ws + OFF_ED);
    int*   em    = (int*)(ws + OFF_EM);
    float* z     = (float*)(ws + OFF_Z);
    int*   coff  = (int*)(ws + OFF_COFF);
    int*   cdeg  = (int*)(ws + OFF_CDEG);
    int*   csrc  = (int*)(ws + OFF_CSRC);
    unsigned short* w1h = (unsigned short*)(ws + OFF_W1H);
    unsigned short* w1l = (unsigned short*)(ws + OFF_W1L);
    unsigned short* w2h = (unsigned short*)(ws + OFF_W2H);
    unsigned short* w2l = (unsigned short*)(ws + OFF_W2L);
    unsigned short* w3h = (unsigned short*)(ws + OFF_W3H);
    unsigned short* w3l = (unsigned short*)(ws + OFF_W3L);

    hipMemsetAsync(z, 0, 128ull * 256 * 4, stream);
    prep_w_all<<<dim3(13, 16, 3), 64, 0, stream>>>(
        Wrel1, Wroot1, Wrel2, Wroot2, Wrel3, Wroot3,
        w1h, w1l, w2h, w2l, w3h, w3l);
    csr_build0<<<BATCH, 1024, 0, stream>>>(edge_src, edge_dst, coff, cdeg, csrc);

    // ---------- layer 1 ----------
    gemm_wave<13, F_IN><<<1600, 256, 0, stream>>>(x, w1h, w1l, t_rel, h);
    agg_score<<<51200 / 4, 256, 0, stream>>>(t_rel, coff, cdeg, csrc, b1, pw1,
                                             h, sc, NPER);
    topk_pool<<<BATCH, 1024, 0, stream>>>(sc, h, hp, z, edge_src, edge_dst,
                                          es, ed, em, coff, cdeg, csrc,
                                          NPER, K1, 0);

    // ---------- layer 2 ----------
    gemm_wave<4, HD><<<1280, 256, 0, stream>>>(hp, w2h, w2l, t_rel, h);
    agg_score<<<40960 / 4, 256, 0, stream>>>(t_rel, coff, cdeg, csrc, b2, pw2,
                                             h, sc, K1);
    topk_pool<<<BATCH, 1024, 0, stream>>>(sc, h, hp, z, nullptr, nullptr,
                                          es, ed, em, coff, cdeg, csrc,
                                          K1, K2, 1);

    // ---------- layer 3 ----------
    gemm_wave<4, HD><<<1024, 256, 0, stream>>>(hp, w3h, w3l, t_rel, h);
    agg_score<<<32768 / 4, 256, 0, stream>>>(t_rel, coff, cdeg, csrc, b3, pw3,
                                             h, sc, K2);
    topk_pool<<<BATCH, 1024, 0, stream>>>(sc, h, nullptr, z, nullptr, nullptr,
                                          es, ed, em, coff, cdeg, csrc,
                                          K2, K3, 2);

    // ---------- MLP head ----------
    mlp_head<<<BATCH, 256, 0, stream>>>(z, W1, bl1, W2, bl2, W3, bl3, (float*)d_out);
}

// Round 6
// 438.838 us; speedup vs baseline: 1.1134x; 1.1134x over previous
//
#include <hip/hip_runtime.h>
#include <math.h>

// Problem constants
#define BATCH 128
#define NPER 400
#define EPG 6400
#define NEDGE 819200
#define F_IN 400
#define HD 128
#define K1 320
#define K2 256
#define K3 205

typedef __bf16 bf16x8 __attribute__((ext_vector_type(8)));
typedef float f32x4 __attribute__((ext_vector_type(4)));

__device__ __forceinline__ unsigned short f2bf(float f) {
    unsigned u = __builtin_bit_cast(unsigned, f);
    unsigned r = u + 0x7fffu + ((u >> 16) & 1u);
    return (unsigned short)(r >> 16);
}
__device__ __forceinline__ float bf2f(unsigned short s) {
    unsigned u = ((unsigned)s) << 16;
    return __builtin_bit_cast(float, u);
}

// ---------------- workspace layout ----------------
static constexpr size_t SZ_TREL = 51200ull * 128 * 4;
static constexpr size_t OFF_TREL = 0;
static constexpr size_t OFF_H    = OFF_TREL + SZ_TREL;
static constexpr size_t OFF_HP   = OFF_H + SZ_TREL;
static constexpr size_t OFF_SC   = OFF_HP + 40960ull * 128 * 4;
static constexpr size_t OFF_ES   = OFF_SC + 51200ull * 4;
static constexpr size_t OFF_ED   = OFF_ES + (size_t)NEDGE * 4;
static constexpr size_t OFF_EM   = OFF_ED + (size_t)NEDGE * 4;
static constexpr size_t OFF_Z    = OFF_EM + (size_t)NEDGE * 4;
static constexpr size_t OFF_COFF = OFF_Z + 128ull * 256 * 4;
static constexpr size_t OFF_CDEG = OFF_COFF + 51200ull * 4;
static constexpr size_t OFF_CSRC = OFF_CDEG + 51200ull * 4;
static constexpr size_t OFF_W1H  = OFF_CSRC + (size_t)NEDGE * 4;   // 16*13*512 shorts
static constexpr size_t OFF_W1L  = OFF_W1H + 16ull * 13 * 512 * 2;
static constexpr size_t OFF_W2H  = OFF_W1L + 16ull * 13 * 512 * 2;
static constexpr size_t OFF_W2L  = OFF_W2H + 16ull * 4 * 512 * 2;
static constexpr size_t OFF_W3H  = OFF_W2L + 16ull * 4 * 512 * 2;
static constexpr size_t OFF_W3L  = OFF_W3H + 16ull * 4 * 512 * 2;

// ---------------- weight split + fragment-tile prep (all 3 layers) ---------
// chunk[(n_tile*Ks + s)*512 + lane*8 + e] = B[n_tile*16 + (lane&15)][s*32 + (lane>>4)*8 + e]
__global__ __launch_bounds__(64) void prep_w_all(
    const float* __restrict__ Wrel1, const float* __restrict__ Wroot1,
    const float* __restrict__ Wrel2, const float* __restrict__ Wroot2,
    const float* __restrict__ Wrel3, const float* __restrict__ Wroot3,
    unsigned short* __restrict__ b1h, unsigned short* __restrict__ b1l,
    unsigned short* __restrict__ b2h, unsigned short* __restrict__ b2l,
    unsigned short* __restrict__ b3h, unsigned short* __restrict__ b3l) {
    const int layer = blockIdx.z;
    const int s = blockIdx.x;
    const int ntile = blockIdx.y;
    const int Ks = (layer == 0) ? 13 : 4;
    const int Kd = (layer == 0) ? F_IN : HD;
    if (s >= Ks) return;
    const float* Wrel  = (layer == 0) ? Wrel1  : (layer == 1) ? Wrel2  : Wrel3;
    const float* Wroot = (layer == 0) ? Wroot1 : (layer == 1) ? Wroot2 : Wroot3;
    unsigned short* bh = (layer == 0) ? b1h : (layer == 1) ? b2h : b3h;
    unsigned short* bl = (layer == 0) ? b1l : (layer == 1) ? b2l : b3l;
    const int t = threadIdx.x;
    const int rowin = t & 15, qd = t >> 4;
    const int n = ntile * 16 + rowin;
    const int k = s * 32 + qd * 8;
    const float* src = (n < 128) ? &Wrel[(n & 127) * Kd] : &Wroot[(n & 127) * Kd];
    unsigned short hv[8], lv[8];
#pragma unroll
    for (int e = 0; e < 8; e++) {
        float f = (k + e < Kd) ? src[k + e] : 0.f;
        unsigned short hi = f2bf(f);
        hv[e] = hi;
        lv[e] = f2bf(f - bf2f(hi));
    }
    size_t o = ((size_t)ntile * Ks + s) * 512 + (size_t)t * 8;
#pragma unroll
    for (int e = 0; e < 8; e++) { bh[o + e] = hv[e]; bl[o + e] = lv[e]; }
}

// ---------------- MFMA GEMM (split-once-in-LDS bf16 fragment buffer) -------
// Round-4 verified version (best measured). 4 waves share 64 A-rows; A-tile
// reg-staged 2 ahead, converted once to bf16 hi/lo by the whole block,
// ds_written fragment-linear; waves ds_read MFMA-ready fragments.
template <int Ks, int Kd>
__global__ __launch_bounds__(256, 3) void gemm_mfma(
    const float* __restrict__ A,
    const unsigned short* __restrict__ bh_p, const unsigned short* __restrict__ bl_p,
    float* __restrict__ t_rel, float* __restrict__ h) {
    __shared__ char Alds[2][8192];   // [buf][hi 4KB | lo 4KB]
    const int tid = threadIdx.x;
    const int lane = tid & 63;
    const int wv = tid >> 6;
    const int lm = lane & 15;
    const int qd = (lane >> 4) & 3;
    const int m0 = blockIdx.x * 64;
    const int nt0 = wv * 4;

    // staging: thread owns row srow = tid>>2 (0..63), k-quarter sqd = tid&3
    const int srow = tid >> 2;
    const int sqd = tid & 3;
    const int woff = ((srow >> 4) << 10) + (sqd << 8) + ((srow & 15) << 4);
    const float* Arow = A + (size_t)(m0 + srow) * Kd + sqd * 8;

    f32x4 acc[4][4];
#pragma unroll
    for (int i = 0; i < 4; i++)
#pragma unroll
        for (int j = 0; j < 4; j++) acc[i][j] = (f32x4){0.f, 0.f, 0.f, 0.f};

    auto gload = [&](int s, float4& x0, float4& x1) {
        if (s * 32 + sqd * 8 < Kd) {   // Kd % 8 == 0: per-thread all-or-nothing
            const float* p = Arow + s * 32;
            x0 = *(const float4*)p;
            x1 = *(const float4*)(p + 4);
        } else {
            x0 = make_float4(0.f, 0.f, 0.f, 0.f);
            x1 = x0;
        }
    };
    auto cvwrite = [&](int buf, const float4& x0, const float4& x1) {
        float fe[8] = {x0.x, x0.y, x0.z, x0.w, x1.x, x1.y, x1.z, x1.w};
        bf16x8 hv, lv;
#pragma unroll
        for (int e = 0; e < 8; e++) {
            __bf16 hb = (__bf16)fe[e];
            hv[e] = hb;
            lv[e] = (__bf16)(fe[e] - (float)hb);
        }
        *(bf16x8*)(&Alds[buf][woff]) = hv;
        *(bf16x8*)(&Alds[buf][4096 + woff]) = lv;
    };

    // prologue: tiles 0 and 1 into regs, convert tile 0 into buf0
    float4 r0a, r0b, r1a, r1b;   // reg buffer parity: tile s -> (s&1)
    gload(0, r0a, r0b);
    if (Ks > 1) gload(1, r1a, r1b);
    cvwrite(0, r0a, r0b);
    asm volatile("s_waitcnt lgkmcnt(0)" ::: "memory");
    __builtin_amdgcn_s_barrier();
    asm volatile("" ::: "memory");

#pragma unroll
    for (int s = 0; s < Ks; ++s) {
        // ---- B fragment loads for THIS step (issued first: latency budget) --
        bf16x8 bhc[4], blc[4];
#pragma unroll
        for (int j = 0; j < 4; j++)
            bhc[j] = *(const bf16x8*)&bh_p[((size_t)(nt0 + j) * Ks + s) * 512 + lane * 8];
#pragma unroll
        for (int j = 0; j < 4; j++)
            blc[j] = *(const bf16x8*)&bl_p[((size_t)(nt0 + j) * Ks + s) * 512 + lane * 8];

        // ---- A fragment ds_reads (lane-linear, conflict-free) ----
        const char* Ab = &Alds[s & 1][0];
        bf16x8 ah[4], al[4];
#pragma unroll
        for (int i = 0; i < 4; i++) {
            ah[i] = *(const bf16x8*)(Ab + i * 1024 + lane * 16);
            al[i] = *(const bf16x8*)(Ab + 4096 + i * 1024 + lane * 16);
        }

        // ---- convert tile s+1 into the other buffer; prefetch tile s+2 ----
        if (s + 1 < Ks) {
            if ((s + 1) & 1) cvwrite((s + 1) & 1, r1a, r1b);
            else             cvwrite((s + 1) & 1, r0a, r0b);
        }
        if (s + 2 < Ks) {
            if ((s + 2) & 1) gload(s + 2, r1a, r1b);
            else             gload(s + 2, r0a, r0b);
        }

        // ---- MFMA: hi*hi + lo*hi + hi*lo (order preserved for numerics) ----
        __builtin_amdgcn_s_setprio(1);
#pragma unroll
        for (int j = 0; j < 4; j++)
#pragma unroll
            for (int i = 0; i < 4; i++)
                acc[i][j] = __builtin_amdgcn_mfma_f32_16x16x32_bf16(
                    ah[i], bhc[j], acc[i][j], 0, 0, 0);
#pragma unroll
        for (int j = 0; j < 4; j++)
#pragma unroll
            for (int i = 0; i < 4; i++)
                acc[i][j] = __builtin_amdgcn_mfma_f32_16x16x32_bf16(
                    al[i], bhc[j], acc[i][j], 0, 0, 0);
#pragma unroll
        for (int j = 0; j < 4; j++)
#pragma unroll
            for (int i = 0; i < 4; i++)
                acc[i][j] = __builtin_amdgcn_mfma_f32_16x16x32_bf16(
                    ah[i], blc[j], acc[i][j], 0, 0, 0);
        __builtin_amdgcn_s_setprio(0);

        // ---- drain LDS ops (writes visible), barrier; vmcnt stays in flight
        asm volatile("s_waitcnt lgkmcnt(0)" ::: "memory");
        __builtin_amdgcn_s_barrier();
        asm volatile("" ::: "memory");
    }
    // ---- epilogue: C/D layout col=lane&15, row=qd*4+reg ----
    float* out = (wv < 2) ? t_rel : h;
    const int colbase = (wv & 1) * 64;
#pragma unroll
    for (int i = 0; i < 4; i++)
#pragma unroll
        for (int j = 0; j < 4; j++) {
            int row = m0 + i * 16 + qd * 4;
            int col = colbase + j * 16 + lm;
#pragma unroll
            for (int r = 0; r < 4; r++)
                out[(size_t)(row + r) * 128 + col] = acc[i][j][r];
        }
}

// ---------------- CSR build for layer 1 (original edges, no mask) ----------
__global__ __launch_bounds__(1024) void csr_build0(
    const int* __restrict__ gsrc, const int* __restrict__ gdst,
    int* __restrict__ csr_off, int* __restrict__ csr_deg, int* __restrict__ csr_src) {
    __shared__ int cnt[NPER];
    __shared__ int cur[NPER];
    __shared__ int sscan[512];
    const int g = blockIdx.x;
    const int t = threadIdx.x;
    for (int i = t; i < NPER; i += 1024) cnt[i] = 0;
    __syncthreads();
    for (int e = t; e < EPG; e += 1024) {
        int dl = gdst[g * EPG + e] - g * NPER;
        atomicAdd(&cnt[dl], 1);
    }
    __syncthreads();
    if (t < 512) sscan[t] = (t < NPER) ? cnt[t] : 0;
    __syncthreads();
    for (int d = 1; d < 512; d <<= 1) {
        int v = 0;
        if (t < 512 && t >= d) v = sscan[t - d];
        __syncthreads();
        if (t < 512 && t >= d) sscan[t] += v;
        __syncthreads();
    }
    if (t < NPER) {
        int excl = (t == 0) ? 0 : sscan[t - 1];
        int st = g * EPG + excl;
        csr_off[g * NPER + t] = st;
        csr_deg[g * NPER + t] = cnt[t];
        cur[t] = st;
    }
    __syncthreads();
    for (int e = t; e < EPG; e += 1024) {
        int eg = g * EPG + e;
        int dl = gdst[eg] - g * NPER;
        int slot = atomicAdd(&cur[dl], 1);
        csr_src[slot] = gsrc[eg];
    }
}

// ---------------- Aggregation (gather) + combine + relu + score ------------
__global__ __launch_bounds__(256) void agg_score(
    const float* __restrict__ t_rel,
    const int* __restrict__ csr_off, const int* __restrict__ csr_deg,
    const int* __restrict__ csr_src,
    const float* __restrict__ bias, const float* __restrict__ pw,
    float* __restrict__ h, float* __restrict__ sc, int npg) {
    const int xcd = blockIdx.x & 7;
    const int j = blockIdx.x >> 3;
    const int bpg = npg >> 2;
    const int graph = xcd * (BATCH / 8) + j / bpg;
    const int nblk = j - (j / bpg) * bpg;
    const int wid = graph * npg + nblk * 4 + (threadIdx.x >> 6);
    const int lane = threadIdx.x & 63;

    const int start = csr_off[wid];
    const int deg = csr_deg[wid];
    const size_t fo = (size_t)lane * 2;
    float a0 = 0.f, a1 = 0.f, b0 = 0.f, b1 = 0.f;
    float c0 = 0.f, c1 = 0.f, d0 = 0.f, d1 = 0.f;
    int e = 0;
    for (; e + 4 <= deg; e += 4) {
        int s0 = csr_src[start + e];
        int s1 = csr_src[start + e + 1];
        int s2 = csr_src[start + e + 2];
        int s3 = csr_src[start + e + 3];
        float2 v0 = *(const float2*)&t_rel[(size_t)s0 * 128 + fo];
        float2 v1 = *(const float2*)&t_rel[(size_t)s1 * 128 + fo];
        float2 v2 = *(const float2*)&t_rel[(size_t)s2 * 128 + fo];
        float2 v3 = *(const float2*)&t_rel[(size_t)s3 * 128 + fo];
        a0 += v0.x; a1 += v0.y;
        b0 += v1.x; b1 += v1.y;
        c0 += v2.x; c1 += v2.y;
        d0 += v3.x; d1 += v3.y;
    }
    for (; e < deg; e++) {
        int s0 = csr_src[start + e];
        float2 v0 = *(const float2*)&t_rel[(size_t)s0 * 128 + fo];
        a0 += v0.x; a1 += v0.y;
    }
    a0 += b0 + c0 + d0;
    a1 += b1 + c1 + d1;

    float2 bb = *(const float2*)&bias[fo];
    size_t o = (size_t)wid * 128 + fo;
    float2 hv = *(const float2*)&h[o];
    hv.x = fmaxf(hv.x + a0 + bb.x, 0.f);
    hv.y = fmaxf(hv.y + a1 + bb.y, 0.f);
    *(float2*)&h[o] = hv;
    float2 pp = *(const float2*)&pw[fo];
    float d = hv.x * pp.x + hv.y * pp.y;
    float nr = pp.x * pp.x + pp.y * pp.y;
#pragma unroll
    for (int off = 32; off; off >>= 1) {
        d += __shfl_down(d, off, 64);
        nr += __shfl_down(nr, off, 64);
    }
    if (lane == 0) sc[wid] = d / (sqrtf(nr) + 1e-16f);
}

// ---------------- fused topk + pool/readout + edge-remap/CSR ---------------
// One block per graph, 1024 threads. mode: 0=L1 (edges from gsrc/gdst),
// 1=L2 (edges from es/ed/em in-place), 2=L3 (no remap, no hp write).
// Phase 1 is RANK-SELECTION (not bitonic): rank[t] = #{j : s_j ranks before
// s_t} with index tiebreak -- identical total order to the previous bitonic
// sort, but O(n^2) broadcast-friendly LDS reads and ZERO barriers instead of
// ~90 block-wide barriers.
__global__ __launch_bounds__(1024) void topk_pool(
    const float* __restrict__ sc, const float* __restrict__ h,
    float* __restrict__ hp, float* __restrict__ z,
    const int* __restrict__ gsrc, const int* __restrict__ gdst,
    int* __restrict__ es, int* __restrict__ ed, int* __restrict__ em,
    int* __restrict__ csr_off, int* __restrict__ csr_deg, int* __restrict__ csr_src,
    int npg, int k, int mode) {
    __shared__ float svals[NPER];
    __shared__ int si[512];
    __shared__ int nid[NPER];
    __shared__ float tgs[K1];
    __shared__ int packed[EPG];
    __shared__ int cnt[K1];
    __shared__ int cur[K1];
    __shared__ int sscan[512];
    __shared__ float pmx[8][128], psm[8][128];
    const int g = blockIdx.x;
    const int t = threadIdx.x;

    // ---- phase 1: rank-based ordering (desc, index tiebreak) ----
    for (int i = t; i < npg; i += 1024) svals[i] = sc[g * npg + i];
    if (t < K1) cnt[t] = 0;
    __syncthreads();
    if (t < npg) {
        const float mine = svals[t];
        int r = 0;
        for (int j4 = 0; j4 < npg; j4 += 4) {
            float4 v = *(const float4*)&svals[j4];
            r += (v.x > mine) ? 1 : ((v.x == mine) & (j4 + 0 < t)) ? 1 : 0;
            r += (v.y > mine) ? 1 : ((v.y == mine) & (j4 + 1 < t)) ? 1 : 0;
            r += (v.z > mine) ? 1 : ((v.z == mine) & (j4 + 2 < t)) ? 1 : 0;
            r += (v.w > mine) ? 1 : ((v.w == mine) & (j4 + 3 < t)) ? 1 : 0;
        }
        nid[t] = (r < k) ? r : -1;
        if (r < k) {
            si[r] = t;
            tgs[r] = tanhf(mine);
        }
    }
    __syncthreads();

    // ---- phase 3: pool + readout (+hp for next layer) ----
    {
        const int f = t & 127;
        const int jq = t >> 7;     // 0..7
        float mx = -INFINITY, sm = 0.f;
        for (int j = jq; j < k; j += 8) {
            float v = h[(size_t)(g * npg + si[j]) * 128 + f] * tgs[j];
            if (mode != 2) hp[(size_t)(g * k + j) * 128 + f] = v;
            mx = fmaxf(mx, v);
            sm += v;
        }
        pmx[jq][f] = mx; psm[jq][f] = sm;
        __syncthreads();
        if (t < 128) {
            mx = pmx[0][t]; sm = psm[0][t];
#pragma unroll
            for (int q = 1; q < 8; q++) {
                mx = fmaxf(mx, pmx[q][t]);
                sm += psm[q][t];
            }
            z[g * 256 + t] += mx;
            z[g * 256 + 128 + t] += sm / (float)k;
        }
    }
    if (mode == 2) return;

    // ---- phase 4: edge remap + CSR build over pooled node space ----
    for (int e = t; e < EPG; e += 1024) {
        int eg = g * EPG + e;
        int sl, dl, m;
        if (mode == 0) { sl = gsrc[eg] - g * NPER; dl = gdst[eg] - g * NPER; m = 1; }
        else           { sl = es[eg]; dl = ed[eg]; m = em[eg]; }
        int ns = nid[sl], nd = nid[dl];
        int keep = (m && ns >= 0 && nd >= 0) ? 1 : 0;
        es[eg] = keep ? ns : 0;
        ed[eg] = keep ? nd : 0;
        em[eg] = keep;
        packed[e] = keep ? (ns | (nd << 16)) : -1;
        if (keep) atomicAdd(&cnt[nd], 1);
    }
    __syncthreads();
    if (t < 512) sscan[t] = (t < k) ? cnt[t] : 0;
    __syncthreads();
    for (int d = 1; d < 512; d <<= 1) {
        int v = 0;
        if (t < 512 && t >= d) v = sscan[t - d];
        __syncthreads();
        if (t < 512 && t >= d) sscan[t] += v;
        __syncthreads();
    }
    if (t < k) {
        int excl = (t == 0) ? 0 : sscan[t - 1];
        int st = g * EPG + excl;
        csr_off[g * k + t] = st;
        csr_deg[g * k + t] = cnt[t];
        cur[t] = st;
    }
    __syncthreads();
    for (int e = t; e < EPG; e += 1024) {
        int p = packed[e];
        if (p >= 0) {
            int ns = p & 0xffff, nd = p >> 16;
            int slot = atomicAdd(&cur[nd], 1);
            csr_src[slot] = g * k + ns;
        }
    }
}

// ---------------- MLP head + log_softmax ----------------
__global__ __launch_bounds__(256) void mlp_head(const float* __restrict__ z,
                                                const float* __restrict__ W1,
                                                const float* __restrict__ bl1,
                                                const float* __restrict__ W2,
                                                const float* __restrict__ bl2,
                                                const float* __restrict__ W3,
                                                const float* __restrict__ bl3,
                                                float* __restrict__ out) {
    __shared__ float zs[256], l1[128], l2[64];
    const int g = blockIdx.x, t = threadIdx.x;
    zs[t] = z[g * 256 + t];
    __syncthreads();
    if (t < 128) {
        float s = bl1[t];
        const float* w = &W1[t * 256];
        for (int i = 0; i < 256; i++) s += w[i] * zs[i];
        l1[t] = fmaxf(s, 0.f);
    }
    __syncthreads();
    if (t < 64) {
        float s = bl2[t];
        const float* w = &W2[t * 128];
        for (int i = 0; i < 128; i++) s += w[i] * l1[i];
        l2[t] = fmaxf(s, 0.f);
    }
    __syncthreads();
    if (t == 0) {
        float a = bl3[0], b = bl3[1];
        for (int i = 0; i < 64; i++) { a += W3[i] * l2[i]; b += W3[64 + i] * l2[i]; }
        float m = fmaxf(a, b);
        float lse = m + logf(expf(a - m) + expf(b - m));
        out[g * 2 + 0] = a - lse;
        out[g * 2 + 1] = b - lse;
    }
}

// ---------------- launch ----------------
extern "C" void kernel_launch(void* const* d_in, const int* in_sizes, int n_in,
                              void* d_out, int out_size, void* d_ws, size_t ws_size,
                              hipStream_t stream) {
    const float* x        = (const float*)d_in[0];
    const int*   edge_src = (const int*)d_in[1];
    const int*   edge_dst = (const int*)d_in[2];
    const float* Wrel1 = (const float*)d_in[4];
    const float* Wroot1= (const float*)d_in[5];
    const float* b1    = (const float*)d_in[6];
    const float* pw1   = (const float*)d_in[7];
    const float* Wrel2 = (const float*)d_in[8];
    const float* Wroot2= (const float*)d_in[9];
    const float* b2    = (const float*)d_in[10];
    const float* pw2   = (const float*)d_in[11];
    const float* Wrel3 = (const float*)d_in[12];
    const float* Wroot3= (const float*)d_in[13];
    const float* b3    = (const float*)d_in[14];
    const float* pw3   = (const float*)d_in[15];
    const float* W1    = (const float*)d_in[16];
    const float* bl1   = (const float*)d_in[17];
    const float* W2    = (const float*)d_in[18];
    const float* bl2   = (const float*)d_in[19];
    const float* W3    = (const float*)d_in[20];
    const float* bl3   = (const float*)d_in[21];

    char* ws = (char*)d_ws;
    float* t_rel = (float*)(ws + OFF_TREL);
    float* h     = (float*)(ws + OFF_H);
    float* hp    = (float*)(ws + OFF_HP);
    float* sc    = (float*)(ws + OFF_SC);
    int*   es    = (int*)(ws + OFF_ES);
    int*   ed    = (int*)(ws + OFF_ED);
    int*   em    = (int*)(ws + OFF_EM);
    float* z     = (float*)(ws + OFF_Z);
    int*   coff  = (int*)(ws + OFF_COFF);
    int*   cdeg  = (int*)(ws + OFF_CDEG);
    int*   csrc  = (int*)(ws + OFF_CSRC);
    unsigned short* w1h = (unsigned short*)(ws + OFF_W1H);
    unsigned short* w1l = (unsigned short*)(ws + OFF_W1L);
    unsigned short* w2h = (unsigned short*)(ws + OFF_W2H);
    unsigned short* w2l = (unsigned short*)(ws + OFF_W2L);
    unsigned short* w3h = (unsigned short*)(ws + OFF_W3H);
    unsigned short* w3l = (unsigned short*)(ws + OFF_W3L);

    hipMemsetAsync(z, 0, 128ull * 256 * 4, stream);
    prep_w_all<<<dim3(13, 16, 3), 64, 0, stream>>>(
        Wrel1, Wroot1, Wrel2, Wroot2, Wrel3, Wroot3,
        w1h, w1l, w2h, w2l, w3h, w3l);
    csr_build0<<<BATCH, 1024, 0, stream>>>(edge_src, edge_dst, coff, cdeg, csrc);

    // ---------- layer 1 ----------
    gemm_mfma<13, F_IN><<<800, 256, 0, stream>>>(x, w1h, w1l, t_rel, h);
    agg_score<<<51200 / 4, 256, 0, stream>>>(t_rel, coff, cdeg, csrc, b1, pw1,
                                             h, sc, NPER);
    topk_pool<<<BATCH, 1024, 0, stream>>>(sc, h, hp, z, edge_src, edge_dst,
                                          es, ed, em, coff, cdeg, csrc,
                                          NPER, K1, 0);

    // ---------- layer 2 ----------
    gemm_mfma<4, HD><<<640, 256, 0, stream>>>(hp, w2h, w2l, t_rel, h);
    agg_score<<<40960 / 4, 256, 0, stream>>>(t_rel, coff, cdeg, csrc, b2, pw2,
                                             h, sc, K1);
    topk_pool<<<BATCH, 1024, 0, stream>>>(sc, h, hp, z, nullptr, nullptr,
                                          es, ed, em, coff, cdeg, csrc,
                                          K1, K2, 1);

    // ---------- layer 3 ----------
    gemm_mfma<4, HD><<<512, 256, 0, stream>>>(hp, w3h, w3l, t_rel, h);
    agg_score<<<32768 / 4, 256, 0, stream>>>(t_rel, coff, cdeg, csrc, b3, pw3,
                                             h, sc, K2);
    topk_pool<<<BATCH, 1024, 0, stream>>>(sc, h, nullptr, z, nullptr, nullptr,
                                          es, ed, em, coff, cdeg, csrc,
                                          K2, K3, 2);

    // ---------- MLP head ----------
    mlp_head<<<BATCH, 256, 0, stream>>>(z, W1, bl1, W2, bl2, W3, bl3, (float*)d_out);
}

// Round 7
// 401.695 us; speedup vs baseline: 1.2164x; 1.0925x over previous
//
#include <hip/hip_runtime.h>
#include <math.h>

// Problem constants
#define BATCH 128
#define NPER 400
#define EPG 6400
#define NEDGE 819200
#define F_IN 400
#define HD 128
#define K1 320
#define K2 256
#define K3 205

typedef __bf16 bf16x8 __attribute__((ext_vector_type(8)));
typedef float f32x4 __attribute__((ext_vector_type(4)));

__device__ __forceinline__ unsigned short f2bf(float f) {
    unsigned u = __builtin_bit_cast(unsigned, f);
    unsigned r = u + 0x7fffu + ((u >> 16) & 1u);
    return (unsigned short)(r >> 16);
}
__device__ __forceinline__ float bf2f(unsigned short s) {
    unsigned u = ((unsigned)s) << 16;
    return __builtin_bit_cast(float, u);
}

// ---------------- workspace layout ----------------
static constexpr size_t SZ_TREL = 51200ull * 128 * 4;
static constexpr size_t OFF_TREL = 0;
static constexpr size_t OFF_H    = OFF_TREL + SZ_TREL;
static constexpr size_t OFF_HP   = OFF_H + SZ_TREL;
static constexpr size_t OFF_SC   = OFF_HP + 40960ull * 128 * 4;
static constexpr size_t OFF_EPK  = OFF_SC + 51200ull * 4;          // packed edges
static constexpr size_t OFF_Z    = OFF_EPK + (size_t)NEDGE * 4 * 3; // (slack kept)
static constexpr size_t OFF_COFF = OFF_Z + 128ull * 256 * 4;
static constexpr size_t OFF_CDEG = OFF_COFF + 51200ull * 4;
static constexpr size_t OFF_CSRC = OFF_CDEG + 51200ull * 4;
static constexpr size_t OFF_W1H  = OFF_CSRC + (size_t)NEDGE * 4;   // 16*13*512 shorts
static constexpr size_t OFF_W1L  = OFF_W1H + 16ull * 13 * 512 * 2;
static constexpr size_t OFF_W2H  = OFF_W1L + 16ull * 13 * 512 * 2;
static constexpr size_t OFF_W2L  = OFF_W2H + 16ull * 4 * 512 * 2;
static constexpr size_t OFF_W3H  = OFF_W2L + 16ull * 4 * 512 * 2;
static constexpr size_t OFF_W3L  = OFF_W3H + 16ull * 4 * 512 * 2;

// ---------------- weight split + fragment-tile prep (all 3 layers) ---------
// chunk[(n_tile*Ks + s)*512 + lane*8 + e] = B[n_tile*16 + (lane&15)][s*32 + (lane>>4)*8 + e]
__global__ __launch_bounds__(64) void prep_w_all(
    const float* __restrict__ Wrel1, const float* __restrict__ Wroot1,
    const float* __restrict__ Wrel2, const float* __restrict__ Wroot2,
    const float* __restrict__ Wrel3, const float* __restrict__ Wroot3,
    unsigned short* __restrict__ b1h, unsigned short* __restrict__ b1l,
    unsigned short* __restrict__ b2h, unsigned short* __restrict__ b2l,
    unsigned short* __restrict__ b3h, unsigned short* __restrict__ b3l) {
    const int layer = blockIdx.z;
    const int s = blockIdx.x;
    const int ntile = blockIdx.y;
    const int Ks = (layer == 0) ? 13 : 4;
    const int Kd = (layer == 0) ? F_IN : HD;
    if (s >= Ks) return;
    const float* Wrel  = (layer == 0) ? Wrel1  : (layer == 1) ? Wrel2  : Wrel3;
    const float* Wroot = (layer == 0) ? Wroot1 : (layer == 1) ? Wroot2 : Wroot3;
    unsigned short* bh = (layer == 0) ? b1h : (layer == 1) ? b2h : b3h;
    unsigned short* bl = (layer == 0) ? b1l : (layer == 1) ? b2l : b3l;
    const int t = threadIdx.x;
    const int rowin = t & 15, qd = t >> 4;
    const int n = ntile * 16 + rowin;
    const int k = s * 32 + qd * 8;
    const float* src = (n < 128) ? &Wrel[(n & 127) * Kd] : &Wroot[(n & 127) * Kd];
    unsigned short hv[8], lv[8];
#pragma unroll
    for (int e = 0; e < 8; e++) {
        float f = (k + e < Kd) ? src[k + e] : 0.f;
        unsigned short hi = f2bf(f);
        hv[e] = hi;
        lv[e] = f2bf(f - bf2f(hi));
    }
    size_t o = ((size_t)ntile * Ks + s) * 512 + (size_t)t * 8;
#pragma unroll
    for (int e = 0; e < 8; e++) { bh[o + e] = hv[e]; bl[o + e] = lv[e]; }
}

// ---------------- MFMA GEMM (split-once-in-LDS bf16 fragment buffer) -------
// Round-4 verified version (best measured). 4 waves share 64 A-rows; A-tile
// reg-staged 2 ahead, converted once to bf16 hi/lo by the whole block,
// ds_written fragment-linear; waves ds_read MFMA-ready fragments.
template <int Ks, int Kd>
__global__ __launch_bounds__(256, 3) void gemm_mfma(
    const float* __restrict__ A,
    const unsigned short* __restrict__ bh_p, const unsigned short* __restrict__ bl_p,
    float* __restrict__ t_rel, float* __restrict__ h) {
    __shared__ char Alds[2][8192];   // [buf][hi 4KB | lo 4KB]
    const int tid = threadIdx.x;
    const int lane = tid & 63;
    const int wv = tid >> 6;
    const int lm = lane & 15;
    const int qd = (lane >> 4) & 3;
    const int m0 = blockIdx.x * 64;
    const int nt0 = wv * 4;

    // staging: thread owns row srow = tid>>2 (0..63), k-quarter sqd = tid&3
    const int srow = tid >> 2;
    const int sqd = tid & 3;
    const int woff = ((srow >> 4) << 10) + (sqd << 8) + ((srow & 15) << 4);
    const float* Arow = A + (size_t)(m0 + srow) * Kd + sqd * 8;

    f32x4 acc[4][4];
#pragma unroll
    for (int i = 0; i < 4; i++)
#pragma unroll
        for (int j = 0; j < 4; j++) acc[i][j] = (f32x4){0.f, 0.f, 0.f, 0.f};

    auto gload = [&](int s, float4& x0, float4& x1) {
        if (s * 32 + sqd * 8 < Kd) {   // Kd % 8 == 0: per-thread all-or-nothing
            const float* p = Arow + s * 32;
            x0 = *(const float4*)p;
            x1 = *(const float4*)(p + 4);
        } else {
            x0 = make_float4(0.f, 0.f, 0.f, 0.f);
            x1 = x0;
        }
    };
    auto cvwrite = [&](int buf, const float4& x0, const float4& x1) {
        float fe[8] = {x0.x, x0.y, x0.z, x0.w, x1.x, x1.y, x1.z, x1.w};
        bf16x8 hv, lv;
#pragma unroll
        for (int e = 0; e < 8; e++) {
            __bf16 hb = (__bf16)fe[e];
            hv[e] = hb;
            lv[e] = (__bf16)(fe[e] - (float)hb);
        }
        *(bf16x8*)(&Alds[buf][woff]) = hv;
        *(bf16x8*)(&Alds[buf][4096 + woff]) = lv;
    };

    // prologue: tiles 0 and 1 into regs, convert tile 0 into buf0
    float4 r0a, r0b, r1a, r1b;   // reg buffer parity: tile s -> (s&1)
    gload(0, r0a, r0b);
    if (Ks > 1) gload(1, r1a, r1b);
    cvwrite(0, r0a, r0b);
    asm volatile("s_waitcnt lgkmcnt(0)" ::: "memory");
    __builtin_amdgcn_s_barrier();
    asm volatile("" ::: "memory");

#pragma unroll
    for (int s = 0; s < Ks; ++s) {
        // ---- B fragment loads for THIS step (issued first: latency budget) --
        bf16x8 bhc[4], blc[4];
#pragma unroll
        for (int j = 0; j < 4; j++)
            bhc[j] = *(const bf16x8*)&bh_p[((size_t)(nt0 + j) * Ks + s) * 512 + lane * 8];
#pragma unroll
        for (int j = 0; j < 4; j++)
            blc[j] = *(const bf16x8*)&bl_p[((size_t)(nt0 + j) * Ks + s) * 512 + lane * 8];

        // ---- A fragment ds_reads (lane-linear, conflict-free) ----
        const char* Ab = &Alds[s & 1][0];
        bf16x8 ah[4], al[4];
#pragma unroll
        for (int i = 0; i < 4; i++) {
            ah[i] = *(const bf16x8*)(Ab + i * 1024 + lane * 16);
            al[i] = *(const bf16x8*)(Ab + 4096 + i * 1024 + lane * 16);
        }

        // ---- convert tile s+1 into the other buffer; prefetch tile s+2 ----
        if (s + 1 < Ks) {
            if ((s + 1) & 1) cvwrite((s + 1) & 1, r1a, r1b);
            else             cvwrite((s + 1) & 1, r0a, r0b);
        }
        if (s + 2 < Ks) {
            if ((s + 2) & 1) gload(s + 2, r1a, r1b);
            else             gload(s + 2, r0a, r0b);
        }

        // ---- MFMA: hi*hi + lo*hi + hi*lo (order preserved for numerics) ----
        __builtin_amdgcn_s_setprio(1);
#pragma unroll
        for (int j = 0; j < 4; j++)
#pragma unroll
            for (int i = 0; i < 4; i++)
                acc[i][j] = __builtin_amdgcn_mfma_f32_16x16x32_bf16(
                    ah[i], bhc[j], acc[i][j], 0, 0, 0);
#pragma unroll
        for (int j = 0; j < 4; j++)
#pragma unroll
            for (int i = 0; i < 4; i++)
                acc[i][j] = __builtin_amdgcn_mfma_f32_16x16x32_bf16(
                    al[i], bhc[j], acc[i][j], 0, 0, 0);
#pragma unroll
        for (int j = 0; j < 4; j++)
#pragma unroll
            for (int i = 0; i < 4; i++)
                acc[i][j] = __builtin_amdgcn_mfma_f32_16x16x32_bf16(
                    ah[i], blc[j], acc[i][j], 0, 0, 0);
        __builtin_amdgcn_s_setprio(0);

        // ---- drain LDS ops (writes visible), barrier; vmcnt stays in flight
        asm volatile("s_waitcnt lgkmcnt(0)" ::: "memory");
        __builtin_amdgcn_s_barrier();
        asm volatile("" ::: "memory");
    }
    // ---- epilogue: C/D layout col=lane&15, row=qd*4+reg ----
    float* out = (wv < 2) ? t_rel : h;
    const int colbase = (wv & 1) * 64;
#pragma unroll
    for (int i = 0; i < 4; i++)
#pragma unroll
        for (int j = 0; j < 4; j++) {
            int row = m0 + i * 16 + qd * 4;
            int col = colbase + j * 16 + lm;
#pragma unroll
            for (int r = 0; r < 4; r++)
                out[(size_t)(row + r) * 128 + col] = acc[i][j][r];
        }
}

// ---------------- CSR build for layer 1 (original edges, no mask) ----------
__global__ __launch_bounds__(1024) void csr_build0(
    const int* __restrict__ gsrc, const int* __restrict__ gdst,
    int* __restrict__ csr_off, int* __restrict__ csr_deg, int* __restrict__ csr_src) {
    __shared__ int cnt[NPER];
    __shared__ int cur[NPER];
    __shared__ int sscan[512];
    const int g = blockIdx.x;
    const int t = threadIdx.x;
    for (int i = t; i < NPER; i += 1024) cnt[i] = 0;
    __syncthreads();
    for (int e = t; e < EPG; e += 1024) {
        int dl = gdst[g * EPG + e] - g * NPER;
        atomicAdd(&cnt[dl], 1);
    }
    __syncthreads();
    if (t < 512) sscan[t] = (t < NPER) ? cnt[t] : 0;
    __syncthreads();
    for (int d = 1; d < 512; d <<= 1) {
        int v = 0;
        if (t < 512 && t >= d) v = sscan[t - d];
        __syncthreads();
        if (t < 512 && t >= d) sscan[t] += v;
        __syncthreads();
    }
    if (t < NPER) {
        int excl = (t == 0) ? 0 : sscan[t - 1];
        int st = g * EPG + excl;
        csr_off[g * NPER + t] = st;
        csr_deg[g * NPER + t] = cnt[t];
        cur[t] = st;
    }
    __syncthreads();
    for (int e = t; e < EPG; e += 1024) {
        int eg = g * EPG + e;
        int dl = gdst[eg] - g * NPER;
        int slot = atomicAdd(&cur[dl], 1);
        csr_src[slot] = gsrc[eg];
    }
}

// ---------------- Aggregation (gather) + combine + relu + score ------------
// One node per 32-lane half-wave (8 nodes/block), float4 per lane covers 128
// features. Same coalescing (512B/edge) but half the memory instructions and
// 2x node TLP vs the old 1-node-per-wave float2 version. Per-feature
// accumulation pattern (4-partial unroll, combine order) kept identical.
__global__ __launch_bounds__(256) void agg_score(
    const float* __restrict__ t_rel,
    const int* __restrict__ csr_off, const int* __restrict__ csr_deg,
    const int* __restrict__ csr_src,
    const float* __restrict__ bias, const float* __restrict__ pw,
    float* __restrict__ h, float* __restrict__ sc, int npg) {
    const int xcd = blockIdx.x & 7;
    const int j = blockIdx.x >> 3;
    const int bpg = npg >> 3;             // blocks per graph (npg % 8 == 0)
    const int graph = xcd * (BATCH / 8) + j / bpg;
    const int nblk = j - (j / bpg) * bpg;
    const int hw = threadIdx.x >> 5;      // half-wave 0..7
    const int lane = threadIdx.x & 31;
    const int wid = graph * npg + nblk * 8 + hw;

    const int start = csr_off[wid];
    const int deg = csr_deg[wid];
    const size_t fo = (size_t)lane * 4;
    f32x4 a = {0.f, 0.f, 0.f, 0.f}, b = a, c = a, d4 = a;
    int e = 0;
    for (; e + 4 <= deg; e += 4) {
        int s0 = csr_src[start + e];
        int s1 = csr_src[start + e + 1];
        int s2 = csr_src[start + e + 2];
        int s3 = csr_src[start + e + 3];
        f32x4 v0 = *(const f32x4*)&t_rel[(size_t)s0 * 128 + fo];
        f32x4 v1 = *(const f32x4*)&t_rel[(size_t)s1 * 128 + fo];
        f32x4 v2 = *(const f32x4*)&t_rel[(size_t)s2 * 128 + fo];
        f32x4 v3 = *(const f32x4*)&t_rel[(size_t)s3 * 128 + fo];
        a += v0; b += v1; c += v2; d4 += v3;
    }
    for (; e < deg; e++) {
        int s0 = csr_src[start + e];
        f32x4 v0 = *(const f32x4*)&t_rel[(size_t)s0 * 128 + fo];
        a += v0;
    }
    a += b + c + d4;   // same combine order as before: a + ((b+c)+d)

    f32x4 bb = *(const f32x4*)&bias[fo];
    size_t o = (size_t)wid * 128 + fo;
    f32x4 hv = *(const f32x4*)&h[o];
#pragma unroll
    for (int q = 0; q < 4; q++) hv[q] = fmaxf(hv[q] + a[q] + bb[q], 0.f);
    *(f32x4*)&h[o] = hv;
    f32x4 pp = *(const f32x4*)&pw[fo];
    float d = hv[0] * pp[0] + hv[1] * pp[1] + hv[2] * pp[2] + hv[3] * pp[3];
    float nr = pp[0] * pp[0] + pp[1] * pp[1] + pp[2] * pp[2] + pp[3] * pp[3];
#pragma unroll
    for (int off = 16; off; off >>= 1) {
        d += __shfl_down(d, off, 32);
        nr += __shfl_down(nr, off, 32);
    }
    if (lane == 0) sc[wid] = d / (sqrtf(nr) + 1e-16f);
}

// ---------------- fused topk + pool/readout + edge-remap/CSR ---------------
// One block per graph, 1024 threads. mode: 0=L1 (edges from gsrc/gdst),
// 1=L2 (edges from packed epk in-place), 2=L3 (no remap, no hp write).
// Edge state between layers is ONE packed int per edge: ns | nd<<10 | m<<20
// (ns,nd < 512) -- 3x less HBM traffic than separate es/ed/em arrays.
__global__ __launch_bounds__(1024) void topk_pool(
    const float* __restrict__ sc, const float* __restrict__ h,
    float* __restrict__ hp, float* __restrict__ z,
    const int* __restrict__ gsrc, const int* __restrict__ gdst,
    int* __restrict__ epk,
    int* __restrict__ csr_off, int* __restrict__ csr_deg, int* __restrict__ csr_src,
    int npg, int k, int mode) {
    __shared__ float svals[NPER];
    __shared__ int si[512];
    __shared__ int nid[NPER];
    __shared__ float tgs[K1];
    __shared__ int packed[EPG];
    __shared__ int cnt[K1];
    __shared__ int cur[K1];
    __shared__ int sscan[512];
    __shared__ float pmx[8][128], psm[8][128];
    const int g = blockIdx.x;
    const int t = threadIdx.x;

    // ---- phase 1: rank-based ordering (desc, index tiebreak), no barriers --
    for (int i = t; i < npg; i += 1024) svals[i] = sc[g * npg + i];
    if (t < K1) cnt[t] = 0;
    __syncthreads();
    if (t < npg) {
        const float mine = svals[t];
        int r = 0;
        for (int j4 = 0; j4 < npg; j4 += 4) {
            float4 v = *(const float4*)&svals[j4];
            r += (v.x > mine) ? 1 : ((v.x == mine) & (j4 + 0 < t)) ? 1 : 0;
            r += (v.y > mine) ? 1 : ((v.y == mine) & (j4 + 1 < t)) ? 1 : 0;
            r += (v.z > mine) ? 1 : ((v.z == mine) & (j4 + 2 < t)) ? 1 : 0;
            r += (v.w > mine) ? 1 : ((v.w == mine) & (j4 + 3 < t)) ? 1 : 0;
        }
        nid[t] = (r < k) ? r : -1;
        if (r < k) {
            si[r] = t;
            tgs[r] = tanhf(mine);
        }
    }
    __syncthreads();

    // ---- phase 3: pool + readout (+hp for next layer) ----
    {
        const int f = t & 127;
        const int jq = t >> 7;     // 0..7
        float mx = -INFINITY, sm = 0.f;
        for (int j = jq; j < k; j += 8) {
            float v = h[(size_t)(g * npg + si[j]) * 128 + f] * tgs[j];
            if (mode != 2) hp[(size_t)(g * k + j) * 128 + f] = v;
            mx = fmaxf(mx, v);
            sm += v;
        }
        pmx[jq][f] = mx; psm[jq][f] = sm;
        __syncthreads();
        if (t < 128) {
            mx = pmx[0][t]; sm = psm[0][t];
#pragma unroll
            for (int q = 1; q < 8; q++) {
                mx = fmaxf(mx, pmx[q][t]);
                sm += psm[q][t];
            }
            z[g * 256 + t] += mx;
            z[g * 256 + 128 + t] += sm / (float)k;
        }
    }
    if (mode == 2) return;

    // ---- phase 4: edge remap + CSR build over pooled node space ----
    for (int e = t; e < EPG; e += 1024) {
        int eg = g * EPG + e;
        int sl, dl, m;
        if (mode == 0) { sl = gsrc[eg] - g * NPER; dl = gdst[eg] - g * NPER; m = 1; }
        else           { int p = epk[eg]; sl = p & 1023; dl = (p >> 10) & 1023; m = p >> 20; }
        int ns = nid[sl], nd = nid[dl];
        int keep = (m && ns >= 0 && nd >= 0) ? 1 : 0;
        epk[eg] = keep ? (ns | (nd << 10) | (1 << 20)) : 0;
        packed[e] = keep ? (ns | (nd << 16)) : -1;
        if (keep) atomicAdd(&cnt[nd], 1);
    }
    __syncthreads();
    if (t < 512) sscan[t] = (t < k) ? cnt[t] : 0;
    __syncthreads();
    for (int d = 1; d < 512; d <<= 1) {
        int v = 0;
        if (t < 512 && t >= d) v = sscan[t - d];
        __syncthreads();
        if (t < 512 && t >= d) sscan[t] += v;
        __syncthreads();
    }
    if (t < k) {
        int excl = (t == 0) ? 0 : sscan[t - 1];
        int st = g * EPG + excl;
        csr_off[g * k + t] = st;
        csr_deg[g * k + t] = cnt[t];
        cur[t] = st;
    }
    __syncthreads();
    for (int e = t; e < EPG; e += 1024) {
        int p = packed[e];
        if (p >= 0) {
            int ns = p & 0xffff, nd = p >> 16;
            int slot = atomicAdd(&cur[nd], 1);
            csr_src[slot] = g * k + ns;
        }
    }
}

// ---------------- MLP head + log_softmax (parallel dots) ----------------
__global__ __launch_bounds__(256) void mlp_head(const float* __restrict__ z,
                                                const float* __restrict__ W1,
                                                const float* __restrict__ bl1,
                                                const float* __restrict__ W2,
                                                const float* __restrict__ bl2,
                                                const float* __restrict__ W3,
                                                const float* __restrict__ bl3,
                                                float* __restrict__ out) {
    __shared__ float zs[256], l1[128], l2[64];
    const int g = blockIdx.x, t = threadIdx.x;
    zs[t] = z[g * 256 + t];
    __syncthreads();
    {   // layer 1: 128 outputs, 2 threads each (halves combined via shfl)
        const int o = t >> 1, half = t & 1;
        const float* w = &W1[o * 256 + half * 128];
        const float* zp = &zs[half * 128];
        float s = 0.f;
        for (int i = 0; i < 128; i++) s += w[i] * zp[i];
        s += __shfl_down(s, 1, 64);
        if (half == 0) l1[o] = fmaxf(s + bl1[o], 0.f);
    }
    __syncthreads();
    {   // layer 2: 64 outputs, 4 threads each
        const int o = t >> 2, q = t & 3;
        const float* w = &W2[o * 128 + q * 32];
        const float* lp = &l1[q * 32];
        float s = 0.f;
        for (int i = 0; i < 32; i++) s += w[i] * lp[i];
        s += __shfl_down(s, 2, 64);
        s += __shfl_down(s, 1, 64);
        if (q == 0) l2[o] = fmaxf(s + bl2[o], 0.f);
    }
    __syncthreads();
    if (t < 64) {   // layer 3 + log_softmax: wave-reduced dots
        float pa = W3[t] * l2[t];
        float pb = W3[64 + t] * l2[t];
#pragma unroll
        for (int off = 32; off; off >>= 1) {
            pa += __shfl_down(pa, off, 64);
            pb += __shfl_down(pb, off, 64);
        }
        if (t == 0) {
            float A = pa + bl3[0], B = pb + bl3[1];
            float m = fmaxf(A, B);
            float lse = m + logf(expf(A - m) + expf(B - m));
            out[g * 2 + 0] = A - lse;
            out[g * 2 + 1] = B - lse;
        }
    }
}

// ---------------- launch ----------------
extern "C" void kernel_launch(void* const* d_in, const int* in_sizes, int n_in,
                              void* d_out, int out_size, void* d_ws, size_t ws_size,
                              hipStream_t stream) {
    const float* x        = (const float*)d_in[0];
    const int*   edge_src = (const int*)d_in[1];
    const int*   edge_dst = (const int*)d_in[2];
    const float* Wrel1 = (const float*)d_in[4];
    const float* Wroot1= (const float*)d_in[5];
    const float* b1    = (const float*)d_in[6];
    const float* pw1   = (const float*)d_in[7];
    const float* Wrel2 = (const float*)d_in[8];
    const float* Wroot2= (const float*)d_in[9];
    const float* b2    = (const float*)d_in[10];
    const float* pw2   = (const float*)d_in[11];
    const float* Wrel3 = (const float*)d_in[12];
    const float* Wroot3= (const float*)d_in[13];
    const float* b3    = (const float*)d_in[14];
    const float* pw3   = (const float*)d_in[15];
    const float* W1    = (const float*)d_in[16];
    const float* bl1   = (const float*)d_in[17];
    const float* W2    = (const float*)d_in[18];
    const float* bl2   = (const float*)d_in[19];
    const float* W3    = (const float*)d_in[20];
    const float* bl3   = (const float*)d_in[21];

    char* ws = (char*)d_ws;
    float* t_rel = (float*)(ws + OFF_TREL);
    float* h     = (float*)(ws + OFF_H);
    float* hp    = (float*)(ws + OFF_HP);
    float* sc    = (float*)(ws + OFF_SC);
    int*   epk   = (int*)(ws + OFF_EPK);
    float* z     = (float*)(ws + OFF_Z);
    int*   coff  = (int*)(ws + OFF_COFF);
    int*   cdeg  = (int*)(ws + OFF_CDEG);
    int*   csrc  = (int*)(ws + OFF_CSRC);
    unsigned short* w1h = (unsigned short*)(ws + OFF_W1H);
    unsigned short* w1l = (unsigned short*)(ws + OFF_W1L);
    unsigned short* w2h = (unsigned short*)(ws + OFF_W2H);
    unsigned short* w2l = (unsigned short*)(ws + OFF_W2L);
    unsigned short* w3h = (unsigned short*)(ws + OFF_W3H);
    unsigned short* w3l = (unsigned short*)(ws + OFF_W3L);

    hipMemsetAsync(z, 0, 128ull * 256 * 4, stream);
    prep_w_all<<<dim3(13, 16, 3), 64, 0, stream>>>(
        Wrel1, Wroot1, Wrel2, Wroot2, Wrel3, Wroot3,
        w1h, w1l, w2h, w2l, w3h, w3l);
    csr_build0<<<BATCH, 1024, 0, stream>>>(edge_src, edge_dst, coff, cdeg, csrc);

    // ---------- layer 1 ----------
    gemm_mfma<13, F_IN><<<800, 256, 0, stream>>>(x, w1h, w1l, t_rel, h);
    agg_score<<<51200 / 8, 256, 0, stream>>>(t_rel, coff, cdeg, csrc, b1, pw1,
                                             h, sc, NPER);
    topk_pool<<<BATCH, 1024, 0, stream>>>(sc, h, hp, z, edge_src, edge_dst,
                                          epk, coff, cdeg, csrc,
                                          NPER, K1, 0);

    // ---------- layer 2 ----------
    gemm_mfma<4, HD><<<640, 256, 0, stream>>>(hp, w2h, w2l, t_rel, h);
    agg_score<<<40960 / 8, 256, 0, stream>>>(t_rel, coff, cdeg, csrc, b2, pw2,
                                             h, sc, K1);
    topk_pool<<<BATCH, 1024, 0, stream>>>(sc, h, hp, z, nullptr, nullptr,
                                          epk, coff, cdeg, csrc,
                                          K1, K2, 1);

    // ---------- layer 3 ----------
    gemm_mfma<4, HD><<<512, 256, 0, stream>>>(hp, w3h, w3l, t_rel, h);
    agg_score<<<32768 / 8, 256, 0, stream>>>(t_rel, coff, cdeg, csrc, b3, pw3,
                                             h, sc, K2);
    topk_pool<<<BATCH, 1024, 0, stream>>>(sc, h, nullptr, z, nullptr, nullptr,
                                          epk, coff, cdeg, csrc,
                                          K2, K3, 2);

    // ---------- MLP head ----------
    mlp_head<<<BATCH, 256, 0, stream>>>(z, W1, bl1, W2, bl2, W3, bl3, (float*)d_out);
}

// Round 8
// 399.816 us; speedup vs baseline: 1.2221x; 1.0047x over previous
//
#include <hip/hip_runtime.h>
#include <math.h>

// Problem constants
#define BATCH 128
#define NPER 400
#define EPG 6400
#define NEDGE 819200
#define F_IN 400
#define HD 128
#define K1 320
#define K2 256
#define K3 205

typedef __bf16 bf16x8 __attribute__((ext_vector_type(8)));
typedef float f32x4 __attribute__((ext_vector_type(4)));

__device__ __forceinline__ unsigned short f2bf(float f) {
    unsigned u = __builtin_bit_cast(unsigned, f);
    unsigned r = u + 0x7fffu + ((u >> 16) & 1u);
    return (unsigned short)(r >> 16);
}
__device__ __forceinline__ float bf2f(unsigned short s) {
    unsigned u = ((unsigned)s) << 16;
    return __builtin_bit_cast(float, u);
}

// ---------------- workspace layout ----------------
static constexpr size_t SZ_TREL = 51200ull * 128 * 4;
static constexpr size_t OFF_TREL = 0;
static constexpr size_t OFF_H    = OFF_TREL + SZ_TREL;
static constexpr size_t OFF_HP   = OFF_H + SZ_TREL;
static constexpr size_t OFF_SC   = OFF_HP + 40960ull * 128 * 4;
static constexpr size_t OFF_EPK  = OFF_SC + 51200ull * 4;          // packed edges
static constexpr size_t OFF_Z    = OFF_EPK + (size_t)NEDGE * 4 * 3; // (slack kept)
static constexpr size_t OFF_COFF = OFF_Z + 128ull * 256 * 4;
static constexpr size_t OFF_CDEG = OFF_COFF + 51200ull * 4;
static constexpr size_t OFF_CSRC = OFF_CDEG + 51200ull * 4;
static constexpr size_t OFF_W1H  = OFF_CSRC + (size_t)NEDGE * 4;   // 16*13*512 shorts
static constexpr size_t OFF_W1L  = OFF_W1H + 16ull * 13 * 512 * 2;
static constexpr size_t OFF_W2H  = OFF_W1L + 16ull * 13 * 512 * 2;
static constexpr size_t OFF_W2L  = OFF_W2H + 16ull * 4 * 512 * 2;
static constexpr size_t OFF_W3H  = OFF_W2L + 16ull * 4 * 512 * 2;
static constexpr size_t OFF_W3L  = OFF_W3H + 16ull * 4 * 512 * 2;

// ---------------- weight split + fragment-tile prep (all 3 layers) ---------
// chunk[(n_tile*Ks + s)*512 + lane*8 + e] = B[n_tile*16 + (lane&15)][s*32 + (lane>>4)*8 + e]
__global__ __launch_bounds__(64) void prep_w_all(
    const float* __restrict__ Wrel1, const float* __restrict__ Wroot1,
    const float* __restrict__ Wrel2, const float* __restrict__ Wroot2,
    const float* __restrict__ Wrel3, const float* __restrict__ Wroot3,
    unsigned short* __restrict__ b1h, unsigned short* __restrict__ b1l,
    unsigned short* __restrict__ b2h, unsigned short* __restrict__ b2l,
    unsigned short* __restrict__ b3h, unsigned short* __restrict__ b3l) {
    const int layer = blockIdx.z;
    const int s = blockIdx.x;
    const int ntile = blockIdx.y;
    const int Ks = (layer == 0) ? 13 : 4;
    const int Kd = (layer == 0) ? F_IN : HD;
    if (s >= Ks) return;
    const float* Wrel  = (layer == 0) ? Wrel1  : (layer == 1) ? Wrel2  : Wrel3;
    const float* Wroot = (layer == 0) ? Wroot1 : (layer == 1) ? Wroot2 : Wroot3;
    unsigned short* bh = (layer == 0) ? b1h : (layer == 1) ? b2h : b3h;
    unsigned short* bl = (layer == 0) ? b1l : (layer == 1) ? b2l : b3l;
    const int t = threadIdx.x;
    const int rowin = t & 15, qd = t >> 4;
    const int n = ntile * 16 + rowin;
    const int k = s * 32 + qd * 8;
    const float* src = (n < 128) ? &Wrel[(n & 127) * Kd] : &Wroot[(n & 127) * Kd];
    unsigned short hv[8], lv[8];
#pragma unroll
    for (int e = 0; e < 8; e++) {
        float f = (k + e < Kd) ? src[k + e] : 0.f;
        unsigned short hi = f2bf(f);
        hv[e] = hi;
        lv[e] = f2bf(f - bf2f(hi));
    }
    size_t o = ((size_t)ntile * Ks + s) * 512 + (size_t)t * 8;
#pragma unroll
    for (int e = 0; e < 8; e++) { bh[o + e] = hv[e]; bl[o + e] = lv[e]; }
}

// ---------------- MFMA GEMM (split-once-in-LDS bf16 fragment buffer) -------
// Round-4 verified structure + XCD-ALIGNED block swizzle: physical block p
// (XCD = p%8) takes logical tile lb = (p%8)*(grid/8) + p/8, so the rows of
// graph g are computed on XCD g/16 -- matching agg_score/topk's consumer
// mapping (row counts align exactly: 400*16=64*100, 320*16=64*80, 256*16=64*64).
// All intermediates (t_rel, h, hp) then stay XCD-local in L2.
template <int Ks, int Kd>
__global__ __launch_bounds__(256, 3) void gemm_mfma(
    const float* __restrict__ A,
    const unsigned short* __restrict__ bh_p, const unsigned short* __restrict__ bl_p,
    float* __restrict__ t_rel, float* __restrict__ h) {
    __shared__ char Alds[2][8192];   // [buf][hi 4KB | lo 4KB]
    const int tid = threadIdx.x;
    const int lane = tid & 63;
    const int wv = tid >> 6;
    const int lm = lane & 15;
    const int qd = (lane >> 4) & 3;
    const int bpx = gridDim.x >> 3;                       // blocks per XCD
    const int lb = ((int)blockIdx.x & 7) * bpx + ((int)blockIdx.x >> 3);
    const int m0 = lb * 64;
    const int nt0 = wv * 4;

    // staging: thread owns row srow = tid>>2 (0..63), k-quarter sqd = tid&3
    const int srow = tid >> 2;
    const int sqd = tid & 3;
    const int woff = ((srow >> 4) << 10) + (sqd << 8) + ((srow & 15) << 4);
    const float* Arow = A + (size_t)(m0 + srow) * Kd + sqd * 8;

    f32x4 acc[4][4];
#pragma unroll
    for (int i = 0; i < 4; i++)
#pragma unroll
        for (int j = 0; j < 4; j++) acc[i][j] = (f32x4){0.f, 0.f, 0.f, 0.f};

    auto gload = [&](int s, float4& x0, float4& x1) {
        if (s * 32 + sqd * 8 < Kd) {   // Kd % 8 == 0: per-thread all-or-nothing
            const float* p = Arow + s * 32;
            x0 = *(const float4*)p;
            x1 = *(const float4*)(p + 4);
        } else {
            x0 = make_float4(0.f, 0.f, 0.f, 0.f);
            x1 = x0;
        }
    };
    auto cvwrite = [&](int buf, const float4& x0, const float4& x1) {
        float fe[8] = {x0.x, x0.y, x0.z, x0.w, x1.x, x1.y, x1.z, x1.w};
        bf16x8 hv, lv;
#pragma unroll
        for (int e = 0; e < 8; e++) {
            __bf16 hb = (__bf16)fe[e];
            hv[e] = hb;
            lv[e] = (__bf16)(fe[e] - (float)hb);
        }
        *(bf16x8*)(&Alds[buf][woff]) = hv;
        *(bf16x8*)(&Alds[buf][4096 + woff]) = lv;
    };

    // prologue: tiles 0 and 1 into regs, convert tile 0 into buf0
    float4 r0a, r0b, r1a, r1b;   // reg buffer parity: tile s -> (s&1)
    gload(0, r0a, r0b);
    if (Ks > 1) gload(1, r1a, r1b);
    cvwrite(0, r0a, r0b);
    asm volatile("s_waitcnt lgkmcnt(0)" ::: "memory");
    __builtin_amdgcn_s_barrier();
    asm volatile("" ::: "memory");

#pragma unroll
    for (int s = 0; s < Ks; ++s) {
        // ---- B fragment loads for THIS step (issued first: latency budget) --
        bf16x8 bhc[4], blc[4];
#pragma unroll
        for (int j = 0; j < 4; j++)
            bhc[j] = *(const bf16x8*)&bh_p[((size_t)(nt0 + j) * Ks + s) * 512 + lane * 8];
#pragma unroll
        for (int j = 0; j < 4; j++)
            blc[j] = *(const bf16x8*)&bl_p[((size_t)(nt0 + j) * Ks + s) * 512 + lane * 8];

        // ---- A fragment ds_reads (lane-linear, conflict-free) ----
        const char* Ab = &Alds[s & 1][0];
        bf16x8 ah[4], al[4];
#pragma unroll
        for (int i = 0; i < 4; i++) {
            ah[i] = *(const bf16x8*)(Ab + i * 1024 + lane * 16);
            al[i] = *(const bf16x8*)(Ab + 4096 + i * 1024 + lane * 16);
        }

        // ---- convert tile s+1 into the other buffer; prefetch tile s+2 ----
        if (s + 1 < Ks) {
            if ((s + 1) & 1) cvwrite((s + 1) & 1, r1a, r1b);
            else             cvwrite((s + 1) & 1, r0a, r0b);
        }
        if (s + 2 < Ks) {
            if ((s + 2) & 1) gload(s + 2, r1a, r1b);
            else             gload(s + 2, r0a, r0b);
        }

        // ---- MFMA: hi*hi + lo*hi + hi*lo (order preserved for numerics) ----
        __builtin_amdgcn_s_setprio(1);
#pragma unroll
        for (int j = 0; j < 4; j++)
#pragma unroll
            for (int i = 0; i < 4; i++)
                acc[i][j] = __builtin_amdgcn_mfma_f32_16x16x32_bf16(
                    ah[i], bhc[j], acc[i][j], 0, 0, 0);
#pragma unroll
        for (int j = 0; j < 4; j++)
#pragma unroll
            for (int i = 0; i < 4; i++)
                acc[i][j] = __builtin_amdgcn_mfma_f32_16x16x32_bf16(
                    al[i], bhc[j], acc[i][j], 0, 0, 0);
#pragma unroll
        for (int j = 0; j < 4; j++)
#pragma unroll
            for (int i = 0; i < 4; i++)
                acc[i][j] = __builtin_amdgcn_mfma_f32_16x16x32_bf16(
                    ah[i], blc[j], acc[i][j], 0, 0, 0);
        __builtin_amdgcn_s_setprio(0);

        // ---- drain LDS ops (writes visible), barrier; vmcnt stays in flight
        asm volatile("s_waitcnt lgkmcnt(0)" ::: "memory");
        __builtin_amdgcn_s_barrier();
        asm volatile("" ::: "memory");
    }
    // ---- epilogue: C/D layout col=lane&15, row=qd*4+reg ----
    float* out = (wv < 2) ? t_rel : h;
    const int colbase = (wv & 1) * 64;
#pragma unroll
    for (int i = 0; i < 4; i++)
#pragma unroll
        for (int j = 0; j < 4; j++) {
            int row = m0 + i * 16 + qd * 4;
            int col = colbase + j * 16 + lm;
#pragma unroll
            for (int r = 0; r < 4; r++)
                out[(size_t)(row + r) * 128 + col] = acc[i][j][r];
        }
}

// ---------------- CSR build for layer 1 (original edges, no mask) ----------
// XCD-aligned: physical block p -> graph (p%8)*16 + p/8, so graph g's CSR
// is built (and cached) on XCD g/16 -- the same XCD agg_score reads it from.
__global__ __launch_bounds__(1024) void csr_build0(
    const int* __restrict__ gsrc, const int* __restrict__ gdst,
    int* __restrict__ csr_off, int* __restrict__ csr_deg, int* __restrict__ csr_src) {
    __shared__ int cnt[NPER];
    __shared__ int cur[NPER];
    __shared__ int sscan[512];
    const int g = ((int)blockIdx.x & 7) * 16 + ((int)blockIdx.x >> 3);
    const int t = threadIdx.x;
    for (int i = t; i < NPER; i += 1024) cnt[i] = 0;
    __syncthreads();
    for (int e = t; e < EPG; e += 1024) {
        int dl = gdst[g * EPG + e] - g * NPER;
        atomicAdd(&cnt[dl], 1);
    }
    __syncthreads();
    if (t < 512) sscan[t] = (t < NPER) ? cnt[t] : 0;
    __syncthreads();
    for (int d = 1; d < 512; d <<= 1) {
        int v = 0;
        if (t < 512 && t >= d) v = sscan[t - d];
        __syncthreads();
        if (t < 512 && t >= d) sscan[t] += v;
        __syncthreads();
    }
    if (t < NPER) {
        int excl = (t == 0) ? 0 : sscan[t - 1];
        int st = g * EPG + excl;
        csr_off[g * NPER + t] = st;
        csr_deg[g * NPER + t] = cnt[t];
        cur[t] = st;
    }
    __syncthreads();
    for (int e = t; e < EPG; e += 1024) {
        int eg = g * EPG + e;
        int dl = gdst[eg] - g * NPER;
        int slot = atomicAdd(&cur[dl], 1);
        csr_src[slot] = gsrc[eg];
    }
}

// ---------------- Aggregation (gather) + combine + relu + score ------------
// One node per 32-lane half-wave (8 nodes/block), float4 per lane covers 128
// features. Graph->XCD mapping (g/16) matches the gemm writer swizzle, so the
// t_rel gather and h read-modify-write hit the LOCAL XCD L2.
__global__ __launch_bounds__(256) void agg_score(
    const float* __restrict__ t_rel,
    const int* __restrict__ csr_off, const int* __restrict__ csr_deg,
    const int* __restrict__ csr_src,
    const float* __restrict__ bias, const float* __restrict__ pw,
    float* __restrict__ h, float* __restrict__ sc, int npg) {
    const int xcd = blockIdx.x & 7;
    const int j = blockIdx.x >> 3;
    const int bpg = npg >> 3;             // blocks per graph (npg % 8 == 0)
    const int graph = xcd * (BATCH / 8) + j / bpg;
    const int nblk = j - (j / bpg) * bpg;
    const int hw = threadIdx.x >> 5;      // half-wave 0..7
    const int lane = threadIdx.x & 31;
    const int wid = graph * npg + nblk * 8 + hw;

    const int start = csr_off[wid];
    const int deg = csr_deg[wid];
    const size_t fo = (size_t)lane * 4;
    f32x4 a = {0.f, 0.f, 0.f, 0.f}, b = a, c = a, d4 = a;
    int e = 0;
    for (; e + 4 <= deg; e += 4) {
        int s0 = csr_src[start + e];
        int s1 = csr_src[start + e + 1];
        int s2 = csr_src[start + e + 2];
        int s3 = csr_src[start + e + 3];
        f32x4 v0 = *(const f32x4*)&t_rel[(size_t)s0 * 128 + fo];
        f32x4 v1 = *(const f32x4*)&t_rel[(size_t)s1 * 128 + fo];
        f32x4 v2 = *(const f32x4*)&t_rel[(size_t)s2 * 128 + fo];
        f32x4 v3 = *(const f32x4*)&t_rel[(size_t)s3 * 128 + fo];
        a += v0; b += v1; c += v2; d4 += v3;
    }
    for (; e < deg; e++) {
        int s0 = csr_src[start + e];
        f32x4 v0 = *(const f32x4*)&t_rel[(size_t)s0 * 128 + fo];
        a += v0;
    }
    a += b + c + d4;   // same combine order as before: a + ((b+c)+d)

    f32x4 bb = *(const f32x4*)&bias[fo];
    size_t o = (size_t)wid * 128 + fo;
    f32x4 hv = *(const f32x4*)&h[o];
#pragma unroll
    for (int q = 0; q < 4; q++) hv[q] = fmaxf(hv[q] + a[q] + bb[q], 0.f);
    *(f32x4*)&h[o] = hv;
    f32x4 pp = *(const f32x4*)&pw[fo];
    float d = hv[0] * pp[0] + hv[1] * pp[1] + hv[2] * pp[2] + hv[3] * pp[3];
    float nr = pp[0] * pp[0] + pp[1] * pp[1] + pp[2] * pp[2] + pp[3] * pp[3];
#pragma unroll
    for (int off = 16; off; off >>= 1) {
        d += __shfl_down(d, off, 32);
        nr += __shfl_down(nr, off, 32);
    }
    if (lane == 0) sc[wid] = d / (sqrtf(nr) + 1e-16f);
}

// ---------------- fused topk + pool/readout + edge-remap/CSR ---------------
// One block per graph (XCD-aligned: graph g on XCD g/16, matching the h/hp/
// CSR producers+consumers), 1024 threads. mode: 0=L1, 1=L2 (packed epk),
// 2=L3 (no remap, no hp write). Edge state between layers is ONE packed int
// per edge: ns | nd<<10 | m<<20.
__global__ __launch_bounds__(1024) void topk_pool(
    const float* __restrict__ sc, const float* __restrict__ h,
    float* __restrict__ hp, float* __restrict__ z,
    const int* __restrict__ gsrc, const int* __restrict__ gdst,
    int* __restrict__ epk,
    int* __restrict__ csr_off, int* __restrict__ csr_deg, int* __restrict__ csr_src,
    int npg, int k, int mode) {
    __shared__ float svals[NPER];
    __shared__ int si[512];
    __shared__ int nid[NPER];
    __shared__ float tgs[K1];
    __shared__ int packed[EPG];
    __shared__ int cnt[K1];
    __shared__ int cur[K1];
    __shared__ int sscan[512];
    __shared__ float pmx[8][128], psm[8][128];
    const int g = ((int)blockIdx.x & 7) * 16 + ((int)blockIdx.x >> 3);
    const int t = threadIdx.x;

    // ---- phase 1: rank-based ordering (desc, index tiebreak), no barriers --
    for (int i = t; i < npg; i += 1024) svals[i] = sc[g * npg + i];
    if (t < K1) cnt[t] = 0;
    __syncthreads();
    if (t < npg) {
        const float mine = svals[t];
        int r = 0;
        for (int j4 = 0; j4 < npg; j4 += 4) {
            float4 v = *(const float4*)&svals[j4];
            r += (v.x > mine) ? 1 : ((v.x == mine) & (j4 + 0 < t)) ? 1 : 0;
            r += (v.y > mine) ? 1 : ((v.y == mine) & (j4 + 1 < t)) ? 1 : 0;
            r += (v.z > mine) ? 1 : ((v.z == mine) & (j4 + 2 < t)) ? 1 : 0;
            r += (v.w > mine) ? 1 : ((v.w == mine) & (j4 + 3 < t)) ? 1 : 0;
        }
        nid[t] = (r < k) ? r : -1;
        if (r < k) {
            si[r] = t;
            tgs[r] = tanhf(mine);
        }
    }
    __syncthreads();

    // ---- phase 3: pool + readout (+hp for next layer) ----
    {
        const int f = t & 127;
        const int jq = t >> 7;     // 0..7
        float mx = -INFINITY, sm = 0.f;
        for (int j = jq; j < k; j += 8) {
            float v = h[(size_t)(g * npg + si[j]) * 128 + f] * tgs[j];
            if (mode != 2) hp[(size_t)(g * k + j) * 128 + f] = v;
            mx = fmaxf(mx, v);
            sm += v;
        }
        pmx[jq][f] = mx; psm[jq][f] = sm;
        __syncthreads();
        if (t < 128) {
            mx = pmx[0][t]; sm = psm[0][t];
#pragma unroll
            for (int q = 1; q < 8; q++) {
                mx = fmaxf(mx, pmx[q][t]);
                sm += psm[q][t];
            }
            z[g * 256 + t] += mx;
            z[g * 256 + 128 + t] += sm / (float)k;
        }
    }
    if (mode == 2) return;

    // ---- phase 4: edge remap + CSR build over pooled node space ----
    for (int e = t; e < EPG; e += 1024) {
        int eg = g * EPG + e;
        int sl, dl, m;
        if (mode == 0) { sl = gsrc[eg] - g * NPER; dl = gdst[eg] - g * NPER; m = 1; }
        else           { int p = epk[eg]; sl = p & 1023; dl = (p >> 10) & 1023; m = p >> 20; }
        int ns = nid[sl], nd = nid[dl];
        int keep = (m && ns >= 0 && nd >= 0) ? 1 : 0;
        epk[eg] = keep ? (ns | (nd << 10) | (1 << 20)) : 0;
        packed[e] = keep ? (ns | (nd << 16)) : -1;
        if (keep) atomicAdd(&cnt[nd], 1);
    }
    __syncthreads();
    if (t < 512) sscan[t] = (t < k) ? cnt[t] : 0;
    __syncthreads();
    for (int d = 1; d < 512; d <<= 1) {
        int v = 0;
        if (t < 512 && t >= d) v = sscan[t - d];
        __syncthreads();
        if (t < 512 && t >= d) sscan[t] += v;
        __syncthreads();
    }
    if (t < k) {
        int excl = (t == 0) ? 0 : sscan[t - 1];
        int st = g * EPG + excl;
        csr_off[g * k + t] = st;
        csr_deg[g * k + t] = cnt[t];
        cur[t] = st;
    }
    __syncthreads();
    for (int e = t; e < EPG; e += 1024) {
        int p = packed[e];
        if (p >= 0) {
            int ns = p & 0xffff, nd = p >> 16;
            int slot = atomicAdd(&cur[nd], 1);
            csr_src[slot] = g * k + ns;
        }
    }
}

// ---------------- MLP head + log_softmax (parallel dots) ----------------
__global__ __launch_bounds__(256) void mlp_head(const float* __restrict__ z,
                                                const float* __restrict__ W1,
                                                const float* __restrict__ bl1,
                                                const float* __restrict__ W2,
                                                const float* __restrict__ bl2,
                                                const float* __restrict__ W3,
                                                const float* __restrict__ bl3,
                                                float* __restrict__ out) {
    __shared__ float zs[256], l1[128], l2[64];
    const int g = blockIdx.x, t = threadIdx.x;
    zs[t] = z[g * 256 + t];
    __syncthreads();
    {   // layer 1: 128 outputs, 2 threads each (halves combined via shfl)
        const int o = t >> 1, half = t & 1;
        const float* w = &W1[o * 256 + half * 128];
        const float* zp = &zs[half * 128];
        float s = 0.f;
        for (int i = 0; i < 128; i++) s += w[i] * zp[i];
        s += __shfl_down(s, 1, 64);
        if (half == 0) l1[o] = fmaxf(s + bl1[o], 0.f);
    }
    __syncthreads();
    {   // layer 2: 64 outputs, 4 threads each
        const int o = t >> 2, q = t & 3;
        const float* w = &W2[o * 128 + q * 32];
        const float* lp = &l1[q * 32];
        float s = 0.f;
        for (int i = 0; i < 32; i++) s += w[i] * lp[i];
        s += __shfl_down(s, 2, 64);
        s += __shfl_down(s, 1, 64);
        if (q == 0) l2[o] = fmaxf(s + bl2[o], 0.f);
    }
    __syncthreads();
    if (t < 64) {   // layer 3 + log_softmax: wave-reduced dots
        float pa = W3[t] * l2[t];
        float pb = W3[64 + t] * l2[t];
#pragma unroll
        for (int off = 32; off; off >>= 1) {
            pa += __shfl_down(pa, off, 64);
            pb += __shfl_down(pb, off, 64);
        }
        if (t == 0) {
            float A = pa + bl3[0], B = pb + bl3[1];
            float m = fmaxf(A, B);
            float lse = m + logf(expf(A - m) + expf(B - m));
            out[g * 2 + 0] = A - lse;
            out[g * 2 + 1] = B - lse;
        }
    }
}

// ---------------- launch ----------------
extern "C" void kernel_launch(void* const* d_in, const int* in_sizes, int n_in,
                              void* d_out, int out_size, void* d_ws, size_t ws_size,
                              hipStream_t stream) {
    const float* x        = (const float*)d_in[0];
    const int*   edge_src = (const int*)d_in[1];
    const int*   edge_dst = (const int*)d_in[2];
    const float* Wrel1 = (const float*)d_in[4];
    const float* Wroot1= (const float*)d_in[5];
    const float* b1    = (const float*)d_in[6];
    const float* pw1   = (const float*)d_in[7];
    const float* Wrel2 = (const float*)d_in[8];
    const float* Wroot2= (const float*)d_in[9];
    const float* b2    = (const float*)d_in[10];
    const float* pw2   = (const float*)d_in[11];
    const float* Wrel3 = (const float*)d_in[12];
    const float* Wroot3= (const float*)d_in[13];
    const float* b3    = (const float*)d_in[14];
    const float* pw3   = (const float*)d_in[15];
    const float* W1    = (const float*)d_in[16];
    const float* bl1   = (const float*)d_in[17];
    const float* W2    = (const float*)d_in[18];
    const float* bl2   = (const float*)d_in[19];
    const float* W3    = (const float*)d_in[20];
    const float* bl3   = (const float*)d_in[21];

    char* ws = (char*)d_ws;
    float* t_rel = (float*)(ws + OFF_TREL);
    float* h     = (float*)(ws + OFF_H);
    float* hp    = (float*)(ws + OFF_HP);
    float* sc    = (float*)(ws + OFF_SC);
    int*   epk   = (int*)(ws + OFF_EPK);
    float* z     = (float*)(ws + OFF_Z);
    int*   coff  = (int*)(ws + OFF_COFF);
    int*   cdeg  = (int*)(ws + OFF_CDEG);
    int*   csrc  = (int*)(ws + OFF_CSRC);
    unsigned short* w1h = (unsigned short*)(ws + OFF_W1H);
    unsigned short* w1l = (unsigned short*)(ws + OFF_W1L);
    unsigned short* w2h = (unsigned short*)(ws + OFF_W2H);
    unsigned short* w2l = (unsigned short*)(ws + OFF_W2L);
    unsigned short* w3h = (unsigned short*)(ws + OFF_W3H);
    unsigned short* w3l = (unsigned short*)(ws + OFF_W3L);

    hipMemsetAsync(z, 0, 128ull * 256 * 4, stream);
    prep_w_all<<<dim3(13, 16, 3), 64, 0, stream>>>(
        Wrel1, Wroot1, Wrel2, Wroot2, Wrel3, Wroot3,
        w1h, w1l, w2h, w2l, w3h, w3l);
    csr_build0<<<BATCH, 1024, 0, stream>>>(edge_src, edge_dst, coff, cdeg, csrc);

    // ---------- layer 1 ----------
    gemm_mfma<13, F_IN><<<800, 256, 0, stream>>>(x, w1h, w1l, t_rel, h);
    agg_score<<<51200 / 8, 256, 0, stream>>>(t_rel, coff, cdeg, csrc, b1, pw1,
                                             h, sc, NPER);
    topk_pool<<<BATCH, 1024, 0, stream>>>(sc, h, hp, z, edge_src, edge_dst,
                                          epk, coff, cdeg, csrc,
                                          NPER, K1, 0);

    // ---------- layer 2 ----------
    gemm_mfma<4, HD><<<640, 256, 0, stream>>>(hp, w2h, w2l, t_rel, h);
    agg_score<<<40960 / 8, 256, 0, stream>>>(t_rel, coff, cdeg, csrc, b2, pw2,
                                             h, sc, K1);
    topk_pool<<<BATCH, 1024, 0, stream>>>(sc, h, hp, z, nullptr, nullptr,
                                          epk, coff, cdeg, csrc,
                                          K1, K2, 1);

    // ---------- layer 3 ----------
    gemm_mfma<4, HD><<<512, 256, 0, stream>>>(hp, w3h, w3l, t_rel, h);
    agg_score<<<32768 / 8, 256, 0, stream>>>(t_rel, coff, cdeg, csrc, b3, pw3,
                                             h, sc, K2);
    topk_pool<<<BATCH, 1024, 0, stream>>>(sc, h, nullptr, z, nullptr, nullptr,
                                          epk, coff, cdeg, csrc,
                                          K2, K3, 2);

    // ---------- MLP head ----------
    mlp_head<<<BATCH, 256, 0, stream>>>(z, W1, bl1, W2, bl2, W3, bl3, (float*)d_out);
}

// Round 9
// 399.573 us; speedup vs baseline: 1.2228x; 1.0006x over previous
//
#include <hip/hip_runtime.h>
#include <math.h>

// Problem constants
#define BATCH 128
#define NPER 400
#define EPG 6400
#define NEDGE 819200
#define F_IN 400
#define HD 128
#define K1 320
#define K2 256
#define K3 205

typedef __bf16 bf16x8 __attribute__((ext_vector_type(8)));
typedef float f32x4 __attribute__((ext_vector_type(4)));

__device__ __forceinline__ unsigned short f2bf(float f) {
    unsigned u = __builtin_bit_cast(unsigned, f);
    unsigned r = u + 0x7fffu + ((u >> 16) & 1u);
    return (unsigned short)(r >> 16);
}
__device__ __forceinline__ float bf2f(unsigned short s) {
    unsigned u = ((unsigned)s) << 16;
    return __builtin_bit_cast(float, u);
}

// ---------------- workspace layout ----------------
static constexpr size_t SZ_TREL = 51200ull * 128 * 4;
static constexpr size_t OFF_TREL = 0;
static constexpr size_t OFF_H    = OFF_TREL + SZ_TREL;
static constexpr size_t OFF_HP   = OFF_H + SZ_TREL;
static constexpr size_t OFF_SC   = OFF_HP + 40960ull * 128 * 4;
static constexpr size_t OFF_EPK  = OFF_SC + 51200ull * 4;          // packed edges
static constexpr size_t OFF_Z    = OFF_EPK + (size_t)NEDGE * 4 * 3; // (slack kept)
static constexpr size_t OFF_COFF = OFF_Z + 128ull * 256 * 4;
static constexpr size_t OFF_CDEG = OFF_COFF + 51200ull * 4;
static constexpr size_t OFF_CSRC = OFF_CDEG + 51200ull * 4;
static constexpr size_t OFF_W1H  = OFF_CSRC + (size_t)NEDGE * 4;   // 16*13*512 shorts
static constexpr size_t OFF_W1L  = OFF_W1H + 16ull * 13 * 512 * 2;
static constexpr size_t OFF_W2H  = OFF_W1L + 16ull * 13 * 512 * 2;
static constexpr size_t OFF_W2L  = OFF_W2H + 16ull * 4 * 512 * 2;
static constexpr size_t OFF_W3H  = OFF_W2L + 16ull * 4 * 512 * 2;
static constexpr size_t OFF_W3L  = OFF_W3H + 16ull * 4 * 512 * 2;

// ---------------- weight split + fragment-tile prep (all 3 layers) ---------
// chunk[(n_tile*Ks + s)*512 + lane*8 + e] = B[n_tile*16 + (lane&15)][s*32 + (lane>>4)*8 + e]
__global__ __launch_bounds__(64) void prep_w_all(
    const float* __restrict__ Wrel1, const float* __restrict__ Wroot1,
    const float* __restrict__ Wrel2, const float* __restrict__ Wroot2,
    const float* __restrict__ Wrel3, const float* __restrict__ Wroot3,
    unsigned short* __restrict__ b1h, unsigned short* __restrict__ b1l,
    unsigned short* __restrict__ b2h, unsigned short* __restrict__ b2l,
    unsigned short* __restrict__ b3h, unsigned short* __restrict__ b3l) {
    const int layer = blockIdx.z;
    const int s = blockIdx.x;
    const int ntile = blockIdx.y;
    const int Ks = (layer == 0) ? 13 : 4;
    const int Kd = (layer == 0) ? F_IN : HD;
    if (s >= Ks) return;
    const float* Wrel  = (layer == 0) ? Wrel1  : (layer == 1) ? Wrel2  : Wrel3;
    const float* Wroot = (layer == 0) ? Wroot1 : (layer == 1) ? Wroot2 : Wroot3;
    unsigned short* bh = (layer == 0) ? b1h : (layer == 1) ? b2h : b3h;
    unsigned short* bl = (layer == 0) ? b1l : (layer == 1) ? b2l : b3l;
    const int t = threadIdx.x;
    const int rowin = t & 15, qd = t >> 4;
    const int n = ntile * 16 + rowin;
    const int k = s * 32 + qd * 8;
    const float* src = (n < 128) ? &Wrel[(n & 127) * Kd] : &Wroot[(n & 127) * Kd];
    unsigned short hv[8], lv[8];
#pragma unroll
    for (int e = 0; e < 8; e++) {
        float f = (k + e < Kd) ? src[k + e] : 0.f;
        unsigned short hi = f2bf(f);
        hv[e] = hi;
        lv[e] = f2bf(f - bf2f(hi));
    }
    size_t o = ((size_t)ntile * Ks + s) * 512 + (size_t)t * 8;
#pragma unroll
    for (int e = 0; e < 8; e++) { bh[o + e] = hv[e]; bl[o + e] = lv[e]; }
}

// ---------------- MFMA GEMM (split-once-in-LDS, post-MFMA convert, 3-deep) --
// Round-8 structure with two scheduling fixes:
//  (a) cvwrite (the ~100-op VALU bf16 split) moved AFTER the MFMA cluster:
//      MFMA starts as soon as ds_read/B retire; the split VALU overlaps
//      OTHER waves' MFMAs (MFMA+VALU pipes co-schedule across waves).
//  (b) 3-deep register staging: gload(s+3) issued in step s, consumed by
//      cvwrite(s+3) in step s+2 -> 2 full steps of HBM-latency cover
//      (was 1 step, which capped step time at the uncovered latency).
// Safety: cvwrite(s+1) targets buf (s+1)&1; all step-(s-1) readers of that
// buffer finished before the step-s barrier (lgkm(0) precedes it).
template <int Ks, int Kd>
__global__ __launch_bounds__(256, 3) void gemm_mfma(
    const float* __restrict__ A,
    const unsigned short* __restrict__ bh_p, const unsigned short* __restrict__ bl_p,
    float* __restrict__ t_rel, float* __restrict__ h) {
    __shared__ char Alds[2][8192];   // [buf][hi 4KB | lo 4KB]
    const int tid = threadIdx.x;
    const int lane = tid & 63;
    const int wv = tid >> 6;
    const int lm = lane & 15;
    const int qd = (lane >> 4) & 3;
    const int bpx = gridDim.x >> 3;                       // blocks per XCD
    const int lb = ((int)blockIdx.x & 7) * bpx + ((int)blockIdx.x >> 3);
    const int m0 = lb * 64;
    const int nt0 = wv * 4;

    // staging: thread owns row srow = tid>>2 (0..63), k-quarter sqd = tid&3
    const int srow = tid >> 2;
    const int sqd = tid & 3;
    const int woff = ((srow >> 4) << 10) + (sqd << 8) + ((srow & 15) << 4);
    const float* Arow = A + (size_t)(m0 + srow) * Kd + sqd * 8;

    f32x4 acc[4][4];
#pragma unroll
    for (int i = 0; i < 4; i++)
#pragma unroll
        for (int j = 0; j < 4; j++) acc[i][j] = (f32x4){0.f, 0.f, 0.f, 0.f};

    auto gload = [&](int s, float4& x0, float4& x1) {
        if (s * 32 + sqd * 8 < Kd) {   // Kd % 8 == 0: per-thread all-or-nothing
            const float* p = Arow + s * 32;
            x0 = *(const float4*)p;
            x1 = *(const float4*)(p + 4);
        } else {
            x0 = make_float4(0.f, 0.f, 0.f, 0.f);
            x1 = x0;
        }
    };
    auto cvwrite = [&](int buf, const float4& x0, const float4& x1) {
        float fe[8] = {x0.x, x0.y, x0.z, x0.w, x1.x, x1.y, x1.z, x1.w};
        bf16x8 hv, lv;
#pragma unroll
        for (int e = 0; e < 8; e++) {
            __bf16 hb = (__bf16)fe[e];
            hv[e] = hb;
            lv[e] = (__bf16)(fe[e] - (float)hb);
        }
        *(bf16x8*)(&Alds[buf][woff]) = hv;
        *(bf16x8*)(&Alds[buf][4096 + woff]) = lv;
    };

    // 3 register staging buffers; tile s lives in slot s%3 (static after unroll)
    float4 r0a, r0b, r1a, r1b, r2a, r2b;
    gload(0, r0a, r0b);
    if (Ks > 1) gload(1, r1a, r1b);
    if (Ks > 2) gload(2, r2a, r2b);
    cvwrite(0, r0a, r0b);
    asm volatile("s_waitcnt lgkmcnt(0)" ::: "memory");
    __builtin_amdgcn_s_barrier();
    asm volatile("" ::: "memory");

#pragma unroll
    for (int s = 0; s < Ks; ++s) {
        // ---- B fragment loads for THIS step (issued first: latency budget) --
        bf16x8 bhc[4], blc[4];
#pragma unroll
        for (int j = 0; j < 4; j++)
            bhc[j] = *(const bf16x8*)&bh_p[((size_t)(nt0 + j) * Ks + s) * 512 + lane * 8];
#pragma unroll
        for (int j = 0; j < 4; j++)
            blc[j] = *(const bf16x8*)&bl_p[((size_t)(nt0 + j) * Ks + s) * 512 + lane * 8];

        // ---- A fragment ds_reads (lane-linear, conflict-free) ----
        const char* Ab = &Alds[s & 1][0];
        bf16x8 ah[4], al[4];
#pragma unroll
        for (int i = 0; i < 4; i++) {
            ah[i] = *(const bf16x8*)(Ab + i * 1024 + lane * 16);
            al[i] = *(const bf16x8*)(Ab + 4096 + i * 1024 + lane * 16);
        }

        // ---- MFMA: hi*hi + lo*hi + hi*lo (order preserved for numerics) ----
        __builtin_amdgcn_s_setprio(1);
#pragma unroll
        for (int j = 0; j < 4; j++)
#pragma unroll
            for (int i = 0; i < 4; i++)
                acc[i][j] = __builtin_amdgcn_mfma_f32_16x16x32_bf16(
                    ah[i], bhc[j], acc[i][j], 0, 0, 0);
#pragma unroll
        for (int j = 0; j < 4; j++)
#pragma unroll
            for (int i = 0; i < 4; i++)
                acc[i][j] = __builtin_amdgcn_mfma_f32_16x16x32_bf16(
                    al[i], bhc[j], acc[i][j], 0, 0, 0);
#pragma unroll
        for (int j = 0; j < 4; j++)
#pragma unroll
            for (int i = 0; i < 4; i++)
                acc[i][j] = __builtin_amdgcn_mfma_f32_16x16x32_bf16(
                    ah[i], blc[j], acc[i][j], 0, 0, 0);
        __builtin_amdgcn_s_setprio(0);

        // ---- AFTER MFMA: convert tile s+1 into other buffer; gload s+3 ----
        if (s + 1 < Ks) {
            const int p1 = (s + 1) % 3;
            if (p1 == 0)      cvwrite((s + 1) & 1, r0a, r0b);
            else if (p1 == 1) cvwrite((s + 1) & 1, r1a, r1b);
            else              cvwrite((s + 1) & 1, r2a, r2b);
        }
        if (s + 3 < Ks) {
            const int p3 = (s + 3) % 3;
            if (p3 == 0)      gload(s + 3, r0a, r0b);
            else if (p3 == 1) gload(s + 3, r1a, r1b);
            else              gload(s + 3, r2a, r2b);
        }

        // ---- drain LDS ops (writes visible), barrier; vmcnt stays in flight
        asm volatile("s_waitcnt lgkmcnt(0)" ::: "memory");
        __builtin_amdgcn_s_barrier();
        asm volatile("" ::: "memory");
    }
    // ---- epilogue: C/D layout col=lane&15, row=qd*4+reg ----
    float* out = (wv < 2) ? t_rel : h;
    const int colbase = (wv & 1) * 64;
#pragma unroll
    for (int i = 0; i < 4; i++)
#pragma unroll
        for (int j = 0; j < 4; j++) {
            int row = m0 + i * 16 + qd * 4;
            int col = colbase + j * 16 + lm;
#pragma unroll
            for (int r = 0; r < 4; r++)
                out[(size_t)(row + r) * 128 + col] = acc[i][j][r];
        }
}

// ---------------- CSR build for layer 1 (original edges, no mask) ----------
__global__ __launch_bounds__(1024) void csr_build0(
    const int* __restrict__ gsrc, const int* __restrict__ gdst,
    int* __restrict__ csr_off, int* __restrict__ csr_deg, int* __restrict__ csr_src) {
    __shared__ int cnt[NPER];
    __shared__ int cur[NPER];
    __shared__ int sscan[512];
    const int g = ((int)blockIdx.x & 7) * 16 + ((int)blockIdx.x >> 3);
    const int t = threadIdx.x;
    for (int i = t; i < NPER; i += 1024) cnt[i] = 0;
    __syncthreads();
    for (int e = t; e < EPG; e += 1024) {
        int dl = gdst[g * EPG + e] - g * NPER;
        atomicAdd(&cnt[dl], 1);
    }
    __syncthreads();
    if (t < 512) sscan[t] = (t < NPER) ? cnt[t] : 0;
    __syncthreads();
    for (int d = 1; d < 512; d <<= 1) {
        int v = 0;
        if (t < 512 && t >= d) v = sscan[t - d];
        __syncthreads();
        if (t < 512 && t >= d) sscan[t] += v;
        __syncthreads();
    }
    if (t < NPER) {
        int excl = (t == 0) ? 0 : sscan[t - 1];
        int st = g * EPG + excl;
        csr_off[g * NPER + t] = st;
        csr_deg[g * NPER + t] = cnt[t];
        cur[t] = st;
    }
    __syncthreads();
    for (int e = t; e < EPG; e += 1024) {
        int eg = g * EPG + e;
        int dl = gdst[eg] - g * NPER;
        int slot = atomicAdd(&cur[dl], 1);
        csr_src[slot] = gsrc[eg];
    }
}

// ---------------- Aggregation (gather) + combine + relu + score ------------
__global__ __launch_bounds__(256) void agg_score(
    const float* __restrict__ t_rel,
    const int* __restrict__ csr_off, const int* __restrict__ csr_deg,
    const int* __restrict__ csr_src,
    const float* __restrict__ bias, const float* __restrict__ pw,
    float* __restrict__ h, float* __restrict__ sc, int npg) {
    const int xcd = blockIdx.x & 7;
    const int j = blockIdx.x >> 3;
    const int bpg = npg >> 3;             // blocks per graph (npg % 8 == 0)
    const int graph = xcd * (BATCH / 8) + j / bpg;
    const int nblk = j - (j / bpg) * bpg;
    const int hw = threadIdx.x >> 5;      // half-wave 0..7
    const int lane = threadIdx.x & 31;
    const int wid = graph * npg + nblk * 8 + hw;

    const int start = csr_off[wid];
    const int deg = csr_deg[wid];
    const size_t fo = (size_t)lane * 4;
    f32x4 a = {0.f, 0.f, 0.f, 0.f}, b = a, c = a, d4 = a;
    int e = 0;
    for (; e + 4 <= deg; e += 4) {
        int s0 = csr_src[start + e];
        int s1 = csr_src[start + e + 1];
        int s2 = csr_src[start + e + 2];
        int s3 = csr_src[start + e + 3];
        f32x4 v0 = *(const f32x4*)&t_rel[(size_t)s0 * 128 + fo];
        f32x4 v1 = *(const f32x4*)&t_rel[(size_t)s1 * 128 + fo];
        f32x4 v2 = *(const f32x4*)&t_rel[(size_t)s2 * 128 + fo];
        f32x4 v3 = *(const f32x4*)&t_rel[(size_t)s3 * 128 + fo];
        a += v0; b += v1; c += v2; d4 += v3;
    }
    for (; e < deg; e++) {
        int s0 = csr_src[start + e];
        f32x4 v0 = *(const f32x4*)&t_rel[(size_t)s0 * 128 + fo];
        a += v0;
    }
    a += b + c + d4;   // same combine order as before: a + ((b+c)+d)

    f32x4 bb = *(const f32x4*)&bias[fo];
    size_t o = (size_t)wid * 128 + fo;
    f32x4 hv = *(const f32x4*)&h[o];
#pragma unroll
    for (int q = 0; q < 4; q++) hv[q] = fmaxf(hv[q] + a[q] + bb[q], 0.f);
    *(f32x4*)&h[o] = hv;
    f32x4 pp = *(const f32x4*)&pw[fo];
    float d = hv[0] * pp[0] + hv[1] * pp[1] + hv[2] * pp[2] + hv[3] * pp[3];
    float nr = pp[0] * pp[0] + pp[1] * pp[1] + pp[2] * pp[2] + pp[3] * pp[3];
#pragma unroll
    for (int off = 16; off; off >>= 1) {
        d += __shfl_down(d, off, 32);
        nr += __shfl_down(nr, off, 32);
    }
    if (lane == 0) sc[wid] = d / (sqrtf(nr) + 1e-16f);
}

// ---------------- fused topk + pool/readout + edge-remap/CSR ---------------
__global__ __launch_bounds__(1024) void topk_pool(
    const float* __restrict__ sc, const float* __restrict__ h,
    float* __restrict__ hp, float* __restrict__ z,
    const int* __restrict__ gsrc, const int* __restrict__ gdst,
    int* __restrict__ epk,
    int* __restrict__ csr_off, int* __restrict__ csr_deg, int* __restrict__ csr_src,
    int npg, int k, int mode) {
    __shared__ float svals[NPER];
    __shared__ int si[512];
    __shared__ int nid[NPER];
    __shared__ float tgs[K1];
    __shared__ int packed[EPG];
    __shared__ int cnt[K1];
    __shared__ int cur[K1];
    __shared__ int sscan[512];
    __shared__ float pmx[8][128], psm[8][128];
    const int g = ((int)blockIdx.x & 7) * 16 + ((int)blockIdx.x >> 3);
    const int t = threadIdx.x;

    // ---- phase 1: rank-based ordering (desc, index tiebreak), no barriers --
    for (int i = t; i < npg; i += 1024) svals[i] = sc[g * npg + i];
    if (t < K1) cnt[t] = 0;
    __syncthreads();
    if (t < npg) {
        const float mine = svals[t];
        int r = 0;
        for (int j4 = 0; j4 < npg; j4 += 4) {
            float4 v = *(const float4*)&svals[j4];
            r += (v.x > mine) ? 1 : ((v.x == mine) & (j4 + 0 < t)) ? 1 : 0;
            r += (v.y > mine) ? 1 : ((v.y == mine) & (j4 + 1 < t)) ? 1 : 0;
            r += (v.z > mine) ? 1 : ((v.z == mine) & (j4 + 2 < t)) ? 1 : 0;
            r += (v.w > mine) ? 1 : ((v.w == mine) & (j4 + 3 < t)) ? 1 : 0;
        }
        nid[t] = (r < k) ? r : -1;
        if (r < k) {
            si[r] = t;
            tgs[r] = tanhf(mine);
        }
    }
    __syncthreads();

    // ---- phase 3: pool + readout (+hp for next layer) ----
    {
        const int f = t & 127;
        const int jq = t >> 7;     // 0..7
        float mx = -INFINITY, sm = 0.f;
        for (int j = jq; j < k; j += 8) {
            float v = h[(size_t)(g * npg + si[j]) * 128 + f] * tgs[j];
            if (mode != 2) hp[(size_t)(g * k + j) * 128 + f] = v;
            mx = fmaxf(mx, v);
            sm += v;
        }
        pmx[jq][f] = mx; psm[jq][f] = sm;
        __syncthreads();
        if (t < 128) {
            mx = pmx[0][t]; sm = psm[0][t];
#pragma unroll
            for (int q = 1; q < 8; q++) {
                mx = fmaxf(mx, pmx[q][t]);
                sm += psm[q][t];
            }
            z[g * 256 + t] += mx;
            z[g * 256 + 128 + t] += sm / (float)k;
        }
    }
    if (mode == 2) return;

    // ---- phase 4: edge remap + CSR build over pooled node space ----
    for (int e = t; e < EPG; e += 1024) {
        int eg = g * EPG + e;
        int sl, dl, m;
        if (mode == 0) { sl = gsrc[eg] - g * NPER; dl = gdst[eg] - g * NPER; m = 1; }
        else           { int p = epk[eg]; sl = p & 1023; dl = (p >> 10) & 1023; m = p >> 20; }
        int ns = nid[sl], nd = nid[dl];
        int keep = (m && ns >= 0 && nd >= 0) ? 1 : 0;
        epk[eg] = keep ? (ns | (nd << 10) | (1 << 20)) : 0;
        packed[e] = keep ? (ns | (nd << 16)) : -1;
        if (keep) atomicAdd(&cnt[nd], 1);
    }
    __syncthreads();
    if (t < 512) sscan[t] = (t < k) ? cnt[t] : 0;
    __syncthreads();
    for (int d = 1; d < 512; d <<= 1) {
        int v = 0;
        if (t < 512 && t >= d) v = sscan[t - d];
        __syncthreads();
        if (t < 512 && t >= d) sscan[t] += v;
        __syncthreads();
    }
    if (t < k) {
        int excl = (t == 0) ? 0 : sscan[t - 1];
        int st = g * EPG + excl;
        csr_off[g * k + t] = st;
        csr_deg[g * k + t] = cnt[t];
        cur[t] = st;
    }
    __syncthreads();
    for (int e = t; e < EPG; e += 1024) {
        int p = packed[e];
        if (p >= 0) {
            int ns = p & 0xffff, nd = p >> 16;
            int slot = atomicAdd(&cur[nd], 1);
            csr_src[slot] = g * k + ns;
        }
    }
}

// ---------------- MLP head + log_softmax (parallel dots) ----------------
__global__ __launch_bounds__(256) void mlp_head(const float* __restrict__ z,
                                                const float* __restrict__ W1,
                                                const float* __restrict__ bl1,
                                                const float* __restrict__ W2,
                                                const float* __restrict__ bl2,
                                                const float* __restrict__ W3,
                                                const float* __restrict__ bl3,
                                                float* __restrict__ out) {
    __shared__ float zs[256], l1[128], l2[64];
    const int g = blockIdx.x, t = threadIdx.x;
    zs[t] = z[g * 256 + t];
    __syncthreads();
    {   // layer 1: 128 outputs, 2 threads each (halves combined via shfl)
        const int o = t >> 1, half = t & 1;
        const float* w = &W1[o * 256 + half * 128];
        const float* zp = &zs[half * 128];
        float s = 0.f;
        for (int i = 0; i < 128; i++) s += w[i] * zp[i];
        s += __shfl_down(s, 1, 64);
        if (half == 0) l1[o] = fmaxf(s + bl1[o], 0.f);
    }
    __syncthreads();
    {   // layer 2: 64 outputs, 4 threads each
        const int o = t >> 2, q = t & 3;
        const float* w = &W2[o * 128 + q * 32];
        const float* lp = &l1[q * 32];
        float s = 0.f;
        for (int i = 0; i < 32; i++) s += w[i] * lp[i];
        s += __shfl_down(s, 2, 64);
        s += __shfl_down(s, 1, 64);
        if (q == 0) l2[o] = fmaxf(s + bl2[o], 0.f);
    }
    __syncthreads();
    if (t < 64) {   // layer 3 + log_softmax: wave-reduced dots
        float pa = W3[t] * l2[t];
        float pb = W3[64 + t] * l2[t];
#pragma unroll
        for (int off = 32; off; off >>= 1) {
            pa += __shfl_down(pa, off, 64);
            pb += __shfl_down(pb, off, 64);
        }
        if (t == 0) {
            float A = pa + bl3[0], B = pb + bl3[1];
            float m = fmaxf(A, B);
            float lse = m + logf(expf(A - m) + expf(B - m));
            out[g * 2 + 0] = A - lse;
            out[g * 2 + 1] = B - lse;
        }
    }
}

// ---------------- launch ----------------
extern "C" void kernel_launch(void* const* d_in, const int* in_sizes, int n_in,
                              void* d_out, int out_size, void* d_ws, size_t ws_size,
                              hipStream_t stream) {
    const float* x        = (const float*)d_in[0];
    const int*   edge_src = (const int*)d_in[1];
    const int*   edge_dst = (const int*)d_in[2];
    const float* Wrel1 = (const float*)d_in[4];
    const float* Wroot1= (const float*)d_in[5];
    const float* b1    = (const float*)d_in[6];
    const float* pw1   = (const float*)d_in[7];
    const float* Wrel2 = (const float*)d_in[8];
    const float* Wroot2= (const float*)d_in[9];
    const float* b2    = (const float*)d_in[10];
    const float* pw2   = (const float*)d_in[11];
    const float* Wrel3 = (const float*)d_in[12];
    const float* Wroot3= (const float*)d_in[13];
    const float* b3    = (const float*)d_in[14];
    const float* pw3   = (const float*)d_in[15];
    const float* W1    = (const float*)d_in[16];
    const float* bl1   = (const float*)d_in[17];
    const float* W2    = (const float*)d_in[18];
    const float* bl2   = (const float*)d_in[19];
    const float* W3    = (const float*)d_in[20];
    const float* bl3   = (const float*)d_in[21];

    char* ws = (char*)d_ws;
    float* t_rel = (float*)(ws + OFF_TREL);
    float* h     = (float*)(ws + OFF_H);
    float* hp    = (float*)(ws + OFF_HP);
    float* sc    = (float*)(ws + OFF_SC);
    int*   epk   = (int*)(ws + OFF_EPK);
    float* z     = (float*)(ws + OFF_Z);
    int*   coff  = (int*)(ws + OFF_COFF);
    int*   cdeg  = (int*)(ws + OFF_CDEG);
    int*   csrc  = (int*)(ws + OFF_CSRC);
    unsigned short* w1h = (unsigned short*)(ws + OFF_W1H);
    unsigned short* w1l = (unsigned short*)(ws + OFF_W1L);
    unsigned short* w2h = (unsigned short*)(ws + OFF_W2H);
    unsigned short* w2l = (unsigned short*)(ws + OFF_W2L);
    unsigned short* w3h = (unsigned short*)(ws + OFF_W3H);
    unsigned short* w3l = (unsigned short*)(ws + OFF_W3L);

    hipMemsetAsync(z, 0, 128ull * 256 * 4, stream);
    prep_w_all<<<dim3(13, 16, 3), 64, 0, stream>>>(
        Wrel1, Wroot1, Wrel2, Wroot2, Wrel3, Wroot3,
        w1h, w1l, w2h, w2l, w3h, w3l);
    csr_build0<<<BATCH, 1024, 0, stream>>>(edge_src, edge_dst, coff, cdeg, csrc);

    // ---------- layer 1 ----------
    gemm_mfma<13, F_IN><<<800, 256, 0, stream>>>(x, w1h, w1l, t_rel, h);
    agg_score<<<51200 / 8, 256, 0, stream>>>(t_rel, coff, cdeg, csrc, b1, pw1,
                                             h, sc, NPER);
    topk_pool<<<BATCH, 1024, 0, stream>>>(sc, h, hp, z, edge_src, edge_dst,
                                          epk, coff, cdeg, csrc,
                                          NPER, K1, 0);

    // ---------- layer 2 ----------
    gemm_mfma<4, HD><<<640, 256, 0, stream>>>(hp, w2h, w2l, t_rel, h);
    agg_score<<<40960 / 8, 256, 0, stream>>>(t_rel, coff, cdeg, csrc, b2, pw2,
                                             h, sc, K1);
    topk_pool<<<BATCH, 1024, 0, stream>>>(sc, h, hp, z, nullptr, nullptr,
                                          epk, coff, cdeg, csrc,
                                          K1, K2, 1);

    // ---------- layer 3 ----------
    gemm_mfma<4, HD><<<512, 256, 0, stream>>>(hp, w3h, w3l, t_rel, h);
    agg_score<<<32768 / 8, 256, 0, stream>>>(t_rel, coff, cdeg, csrc, b3, pw3,
                                             h, sc, K2);
    topk_pool<<<BATCH, 1024, 0, stream>>>(sc, h, nullptr, z, nullptr, nullptr,
                                          epk, coff, cdeg, csrc,
                                          K2, K3, 2);

    // ---------- MLP head ----------
    mlp_head<<<BATCH, 256, 0, stream>>>(z, W1, bl1, W2, bl2, W3, bl3, (float*)d_out);
}

// Round 10
// 381.631 us; speedup vs baseline: 1.2803x; 1.0470x over previous
//
#include <hip/hip_runtime.h>
#include <math.h>

// Problem constants
#define BATCH 128
#define NPER 400
#define EPG 6400
#define NEDGE 819200
#define F_IN 400
#define HD 128
#define K1 320
#define K2 256
#define K3 205

typedef __bf16 bf16x8 __attribute__((ext_vector_type(8)));
typedef float f32x4 __attribute__((ext_vector_type(4)));

__device__ __forceinline__ unsigned short f2bf(float f) {
    unsigned u = __builtin_bit_cast(unsigned, f);
    unsigned r = u + 0x7fffu + ((u >> 16) & 1u);
    return (unsigned short)(r >> 16);
}
__device__ __forceinline__ float bf2f(unsigned short s) {
    unsigned u = ((unsigned)s) << 16;
    return __builtin_bit_cast(float, u);
}

// ---------------- workspace layout ----------------
static constexpr size_t SZ_TREL = 51200ull * 128 * 4;
static constexpr size_t OFF_TREL = 0;
static constexpr size_t OFF_H    = OFF_TREL + SZ_TREL;
static constexpr size_t OFF_HP   = OFF_H + SZ_TREL;
static constexpr size_t OFF_SC   = OFF_HP + 40960ull * 128 * 4;
static constexpr size_t OFF_EPK  = OFF_SC + 51200ull * 4;          // packed edges
static constexpr size_t OFF_Z    = OFF_EPK + (size_t)NEDGE * 4 * 3; // (slack kept)
static constexpr size_t OFF_COFF = OFF_Z + 128ull * 256 * 4;
static constexpr size_t OFF_CDEG = OFF_COFF + 51200ull * 4;
static constexpr size_t OFF_CSRC = OFF_CDEG + 51200ull * 4;
static constexpr size_t OFF_W1H  = OFF_CSRC + (size_t)NEDGE * 4;   // 16*13*512 shorts
static constexpr size_t OFF_W1L  = OFF_W1H + 16ull * 13 * 512 * 2;
static constexpr size_t OFF_W2H  = OFF_W1L + 16ull * 13 * 512 * 2;
static constexpr size_t OFF_W2L  = OFF_W2H + 16ull * 4 * 512 * 2;
static constexpr size_t OFF_W3H  = OFF_W2L + 16ull * 4 * 512 * 2;
static constexpr size_t OFF_W3L  = OFF_W3H + 16ull * 4 * 512 * 2;

// ---------------- weight split + fragment-tile prep (all 3 layers) ---------
__global__ __launch_bounds__(64) void prep_w_all(
    const float* __restrict__ Wrel1, const float* __restrict__ Wroot1,
    const float* __restrict__ Wrel2, const float* __restrict__ Wroot2,
    const float* __restrict__ Wrel3, const float* __restrict__ Wroot3,
    unsigned short* __restrict__ b1h, unsigned short* __restrict__ b1l,
    unsigned short* __restrict__ b2h, unsigned short* __restrict__ b2l,
    unsigned short* __restrict__ b3h, unsigned short* __restrict__ b3l) {
    const int layer = blockIdx.z;
    const int s = blockIdx.x;
    const int ntile = blockIdx.y;
    const int Ks = (layer == 0) ? 13 : 4;
    const int Kd = (layer == 0) ? F_IN : HD;
    if (s >= Ks) return;
    const float* Wrel  = (layer == 0) ? Wrel1  : (layer == 1) ? Wrel2  : Wrel3;
    const float* Wroot = (layer == 0) ? Wroot1 : (layer == 1) ? Wroot2 : Wroot3;
    unsigned short* bh = (layer == 0) ? b1h : (layer == 1) ? b2h : b3h;
    unsigned short* bl = (layer == 0) ? b1l : (layer == 1) ? b2l : b3l;
    const int t = threadIdx.x;
    const int rowin = t & 15, qd = t >> 4;
    const int n = ntile * 16 + rowin;
    const int k = s * 32 + qd * 8;
    const float* src = (n < 128) ? &Wrel[(n & 127) * Kd] : &Wroot[(n & 127) * Kd];
    unsigned short hv[8], lv[8];
#pragma unroll
    for (int e = 0; e < 8; e++) {
        float f = (k + e < Kd) ? src[k + e] : 0.f;
        unsigned short hi = f2bf(f);
        hv[e] = hi;
        lv[e] = f2bf(f - bf2f(hi));
    }
    size_t o = ((size_t)ntile * Ks + s) * 512 + (size_t)t * 8;
#pragma unroll
    for (int e = 0; e < 8; e++) { bh[o + e] = hv[e]; bl[o + e] = lv[e]; }
}

// ---------------- MFMA GEMM (frozen round-9 body) + optional fused CSR -----
// Grid union: blocks [0, gemm_blocks) run the gemm; blocks >= gemm_blocks
// (layer 1 only, FUSE=true) build the per-graph CSR -- the two are data-
// independent, so the CSR work fills CU bubbles in the gemm launch instead
// of serializing as its own half-occupancy launch.
template <int Ks, int Kd, bool FUSE>
__global__ __launch_bounds__(256, 3) void gemm_mfma(
    const float* __restrict__ A,
    const unsigned short* __restrict__ bh_p, const unsigned short* __restrict__ bl_p,
    float* __restrict__ t_rel, float* __restrict__ h, int gemm_blocks,
    const int* __restrict__ gsrc, const int* __restrict__ gdst,
    int* __restrict__ csr_off, int* __restrict__ csr_deg, int* __restrict__ csr_src) {
    if constexpr (FUSE) {
        if ((int)blockIdx.x >= gemm_blocks) {
            // ---- CSR build, 256 threads, one block per graph (XCD-aligned) --
            __shared__ int cnt[NPER];
            __shared__ int cur[NPER];
            __shared__ int sscan[512];
            const int b = (int)blockIdx.x - gemm_blocks;
            const int g = (b & 7) * 16 + (b >> 3);
            const int t = threadIdx.x;
            for (int i = t; i < NPER; i += 256) cnt[i] = 0;
            __syncthreads();
            for (int e = t; e < EPG; e += 256) {
                int dl = gdst[g * EPG + e] - g * NPER;
                atomicAdd(&cnt[dl], 1);
            }
            __syncthreads();
            sscan[t] = (t < NPER) ? cnt[t] : 0;
            sscan[t + 256] = (t + 256 < NPER) ? cnt[t + 256] : 0;
            __syncthreads();
            // inclusive scan of each 256-half, then offset the second half
            for (int d = 1; d < 256; d <<= 1) {
                int va = (t >= d) ? sscan[t - d] : 0;
                int vb = (t >= d) ? sscan[256 + t - d] : 0;
                __syncthreads();
                if (t >= d) { sscan[t] += va; sscan[256 + t] += vb; }
                __syncthreads();
            }
            sscan[256 + t] += sscan[255];   // slot 255 is never written here
            __syncthreads();
            for (int i = t; i < NPER; i += 256) {
                int excl = (i == 0) ? 0 : sscan[i - 1];
                int st = g * EPG + excl;
                csr_off[g * NPER + i] = st;
                csr_deg[g * NPER + i] = cnt[i];
                cur[i] = st;
            }
            __syncthreads();
            for (int e = t; e < EPG; e += 256) {
                int eg = g * EPG + e;
                int dl = gdst[eg] - g * NPER;
                int slot = atomicAdd(&cur[dl], 1);
                csr_src[slot] = gsrc[eg];
            }
            return;
        }
    }
    __shared__ char Alds[2][8192];   // [buf][hi 4KB | lo 4KB]
    const int tid = threadIdx.x;
    const int lane = tid & 63;
    const int wv = tid >> 6;
    const int lm = lane & 15;
    const int qd = (lane >> 4) & 3;
    const int bpx = gemm_blocks >> 3;                     // blocks per XCD
    const int lb = ((int)blockIdx.x & 7) * bpx + ((int)blockIdx.x >> 3);
    const int m0 = lb * 64;
    const int nt0 = wv * 4;

    const int srow = tid >> 2;
    const int sqd = tid & 3;
    const int woff = ((srow >> 4) << 10) + (sqd << 8) + ((srow & 15) << 4);
    const float* Arow = A + (size_t)(m0 + srow) * Kd + sqd * 8;

    f32x4 acc[4][4];
#pragma unroll
    for (int i = 0; i < 4; i++)
#pragma unroll
        for (int j = 0; j < 4; j++) acc[i][j] = (f32x4){0.f, 0.f, 0.f, 0.f};

    auto gload = [&](int s, float4& x0, float4& x1) {
        if (s * 32 + sqd * 8 < Kd) {
            const float* p = Arow + s * 32;
            x0 = *(const float4*)p;
            x1 = *(const float4*)(p + 4);
        } else {
            x0 = make_float4(0.f, 0.f, 0.f, 0.f);
            x1 = x0;
        }
    };
    auto cvwrite = [&](int buf, const float4& x0, const float4& x1) {
        float fe[8] = {x0.x, x0.y, x0.z, x0.w, x1.x, x1.y, x1.z, x1.w};
        bf16x8 hv, lv;
#pragma unroll
        for (int e = 0; e < 8; e++) {
            __bf16 hb = (__bf16)fe[e];
            hv[e] = hb;
            lv[e] = (__bf16)(fe[e] - (float)hb);
        }
        *(bf16x8*)(&Alds[buf][woff]) = hv;
        *(bf16x8*)(&Alds[buf][4096 + woff]) = lv;
    };

    float4 r0a, r0b, r1a, r1b, r2a, r2b;
    gload(0, r0a, r0b);
    if (Ks > 1) gload(1, r1a, r1b);
    if (Ks > 2) gload(2, r2a, r2b);
    cvwrite(0, r0a, r0b);
    asm volatile("s_waitcnt lgkmcnt(0)" ::: "memory");
    __builtin_amdgcn_s_barrier();
    asm volatile("" ::: "memory");

#pragma unroll
    for (int s = 0; s < Ks; ++s) {
        bf16x8 bhc[4], blc[4];
#pragma unroll
        for (int j = 0; j < 4; j++)
            bhc[j] = *(const bf16x8*)&bh_p[((size_t)(nt0 + j) * Ks + s) * 512 + lane * 8];
#pragma unroll
        for (int j = 0; j < 4; j++)
            blc[j] = *(const bf16x8*)&bl_p[((size_t)(nt0 + j) * Ks + s) * 512 + lane * 8];

        const char* Ab = &Alds[s & 1][0];
        bf16x8 ah[4], al[4];
#pragma unroll
        for (int i = 0; i < 4; i++) {
            ah[i] = *(const bf16x8*)(Ab + i * 1024 + lane * 16);
            al[i] = *(const bf16x8*)(Ab + 4096 + i * 1024 + lane * 16);
        }

        __builtin_amdgcn_s_setprio(1);
#pragma unroll
        for (int j = 0; j < 4; j++)
#pragma unroll
            for (int i = 0; i < 4; i++)
                acc[i][j] = __builtin_amdgcn_mfma_f32_16x16x32_bf16(
                    ah[i], bhc[j], acc[i][j], 0, 0, 0);
#pragma unroll
        for (int j = 0; j < 4; j++)
#pragma unroll
            for (int i = 0; i < 4; i++)
                acc[i][j] = __builtin_amdgcn_mfma_f32_16x16x32_bf16(
                    al[i], bhc[j], acc[i][j], 0, 0, 0);
#pragma unroll
        for (int j = 0; j < 4; j++)
#pragma unroll
            for (int i = 0; i < 4; i++)
                acc[i][j] = __builtin_amdgcn_mfma_f32_16x16x32_bf16(
                    ah[i], blc[j], acc[i][j], 0, 0, 0);
        __builtin_amdgcn_s_setprio(0);

        if (s + 1 < Ks) {
            const int p1 = (s + 1) % 3;
            if (p1 == 0)      cvwrite((s + 1) & 1, r0a, r0b);
            else if (p1 == 1) cvwrite((s + 1) & 1, r1a, r1b);
            else              cvwrite((s + 1) & 1, r2a, r2b);
        }
        if (s + 3 < Ks) {
            const int p3 = (s + 3) % 3;
            if (p3 == 0)      gload(s + 3, r0a, r0b);
            else if (p3 == 1) gload(s + 3, r1a, r1b);
            else              gload(s + 3, r2a, r2b);
        }

        asm volatile("s_waitcnt lgkmcnt(0)" ::: "memory");
        __builtin_amdgcn_s_barrier();
        asm volatile("" ::: "memory");
    }
    float* out = (wv < 2) ? t_rel : h;
    const int colbase = (wv & 1) * 64;
#pragma unroll
    for (int i = 0; i < 4; i++)
#pragma unroll
        for (int j = 0; j < 4; j++) {
            int row = m0 + i * 16 + qd * 4;
            int col = colbase + j * 16 + lm;
#pragma unroll
            for (int r = 0; r < 4; r++)
                out[(size_t)(row + r) * 128 + col] = acc[i][j][r];
        }
}

// ---------------- Aggregation (gather) + combine + relu + score ------------
__global__ __launch_bounds__(256) void agg_score(
    const float* __restrict__ t_rel,
    const int* __restrict__ csr_off, const int* __restrict__ csr_deg,
    const int* __restrict__ csr_src,
    const float* __restrict__ bias, const float* __restrict__ pw,
    float* __restrict__ h, float* __restrict__ sc, int npg) {
    const int xcd = blockIdx.x & 7;
    const int j = blockIdx.x >> 3;
    const int bpg = npg >> 3;             // blocks per graph (npg % 8 == 0)
    const int graph = xcd * (BATCH / 8) + j / bpg;
    const int nblk = j - (j / bpg) * bpg;
    const int hw = threadIdx.x >> 5;      // half-wave 0..7
    const int lane = threadIdx.x & 31;
    const int wid = graph * npg + nblk * 8 + hw;

    const int start = csr_off[wid];
    const int deg = csr_deg[wid];
    const size_t fo = (size_t)lane * 4;
    f32x4 a = {0.f, 0.f, 0.f, 0.f}, b = a, c = a, d4 = a;
    int e = 0;
    for (; e + 4 <= deg; e += 4) {
        int s0 = csr_src[start + e];
        int s1 = csr_src[start + e + 1];
        int s2 = csr_src[start + e + 2];
        int s3 = csr_src[start + e + 3];
        f32x4 v0 = *(const f32x4*)&t_rel[(size_t)s0 * 128 + fo];
        f32x4 v1 = *(const f32x4*)&t_rel[(size_t)s1 * 128 + fo];
        f32x4 v2 = *(const f32x4*)&t_rel[(size_t)s2 * 128 + fo];
        f32x4 v3 = *(const f32x4*)&t_rel[(size_t)s3 * 128 + fo];
        a += v0; b += v1; c += v2; d4 += v3;
    }
    for (; e < deg; e++) {
        int s0 = csr_src[start + e];
        f32x4 v0 = *(const f32x4*)&t_rel[(size_t)s0 * 128 + fo];
        a += v0;
    }
    a += b + c + d4;

    f32x4 bb = *(const f32x4*)&bias[fo];
    size_t o = (size_t)wid * 128 + fo;
    f32x4 hv = *(const f32x4*)&h[o];
#pragma unroll
    for (int q = 0; q < 4; q++) hv[q] = fmaxf(hv[q] + a[q] + bb[q], 0.f);
    *(f32x4*)&h[o] = hv;
    f32x4 pp = *(const f32x4*)&pw[fo];
    float d = hv[0] * pp[0] + hv[1] * pp[1] + hv[2] * pp[2] + hv[3] * pp[3];
    float nr = pp[0] * pp[0] + pp[1] * pp[1] + pp[2] * pp[2] + pp[3] * pp[3];
#pragma unroll
    for (int off = 16; off; off >>= 1) {
        d += __shfl_down(d, off, 32);
        nr += __shfl_down(nr, off, 32);
    }
    if (lane == 0) sc[wid] = d / (sqrtf(nr) + 1e-16f);
}

// ---------------- fused topk + pool/readout + edge-remap/CSR (+MLP) --------
// One block per graph (XCD-aligned), 1024 threads. mode: 0=L1, 1=L2 (packed
// epk), 2=L3 (no remap; z finalized in LDS and the MLP head + log_softmax run
// IN THIS BLOCK -- z[g] is complete once this graph's phase 3 is done, so the
// separate mlp_head launch is eliminated).
__global__ __launch_bounds__(1024) void topk_pool(
    const float* __restrict__ sc, const float* __restrict__ h,
    float* __restrict__ hp, float* __restrict__ z,
    const int* __restrict__ gsrc, const int* __restrict__ gdst,
    int* __restrict__ epk,
    int* __restrict__ csr_off, int* __restrict__ csr_deg, int* __restrict__ csr_src,
    int npg, int k, int mode,
    const float* __restrict__ W1, const float* __restrict__ bl1,
    const float* __restrict__ W2, const float* __restrict__ bl2,
    const float* __restrict__ W3, const float* __restrict__ bl3,
    float* __restrict__ outp) {
    __shared__ float svals[NPER];
    __shared__ int si[512];
    __shared__ int nid[NPER];
    __shared__ float tgs[K1];
    __shared__ int packed[EPG];
    __shared__ int cnt[K1];
    __shared__ int cur[K1];
    __shared__ int sscan[512];
    __shared__ float pmx[8][128], psm[8][128];
    __shared__ float zs[256], l1[128], l2[64];
    const int g = ((int)blockIdx.x & 7) * 16 + ((int)blockIdx.x >> 3);
    const int t = threadIdx.x;

    // ---- phase 1: rank-based ordering (desc, index tiebreak), no barriers --
    for (int i = t; i < npg; i += 1024) svals[i] = sc[g * npg + i];
    if (t < K1) cnt[t] = 0;
    __syncthreads();
    if (t < npg) {
        const float mine = svals[t];
        int r = 0;
        for (int j4 = 0; j4 < npg; j4 += 4) {
            float4 v = *(const float4*)&svals[j4];
            r += (v.x > mine) ? 1 : ((v.x == mine) & (j4 + 0 < t)) ? 1 : 0;
            r += (v.y > mine) ? 1 : ((v.y == mine) & (j4 + 1 < t)) ? 1 : 0;
            r += (v.z > mine) ? 1 : ((v.z == mine) & (j4 + 2 < t)) ? 1 : 0;
            r += (v.w > mine) ? 1 : ((v.w == mine) & (j4 + 3 < t)) ? 1 : 0;
        }
        nid[t] = (r < k) ? r : -1;
        if (r < k) {
            si[r] = t;
            tgs[r] = tanhf(mine);
        }
    }
    __syncthreads();

    // ---- phase 3: pool + readout, 4-deep unrolled gather (+hp write) ----
    {
        const int f = t & 127;
        const int jq = t >> 7;     // 0..7
        float mx0 = -INFINITY, mx1 = -INFINITY, mx2 = -INFINITY, mx3 = -INFINITY;
        float sm0 = 0.f, sm1 = 0.f, sm2 = 0.f, sm3 = 0.f;
        int j = jq;
        for (; j + 24 < k; j += 32) {
            int i0 = si[j], i1 = si[j + 8], i2 = si[j + 16], i3 = si[j + 24];
            float v0 = h[(size_t)(g * npg + i0) * 128 + f] * tgs[j];
            float v1 = h[(size_t)(g * npg + i1) * 128 + f] * tgs[j + 8];
            float v2 = h[(size_t)(g * npg + i2) * 128 + f] * tgs[j + 16];
            float v3 = h[(size_t)(g * npg + i3) * 128 + f] * tgs[j + 24];
            if (mode != 2) {
                hp[(size_t)(g * k + j) * 128 + f] = v0;
                hp[(size_t)(g * k + j + 8) * 128 + f] = v1;
                hp[(size_t)(g * k + j + 16) * 128 + f] = v2;
                hp[(size_t)(g * k + j + 24) * 128 + f] = v3;
            }
            mx0 = fmaxf(mx0, v0); sm0 += v0;
            mx1 = fmaxf(mx1, v1); sm1 += v1;
            mx2 = fmaxf(mx2, v2); sm2 += v2;
            mx3 = fmaxf(mx3, v3); sm3 += v3;
        }
        for (; j < k; j += 8) {
            float v = h[(size_t)(g * npg + si[j]) * 128 + f] * tgs[j];
            if (mode != 2) hp[(size_t)(g * k + j) * 128 + f] = v;
            mx0 = fmaxf(mx0, v); sm0 += v;
        }
        pmx[jq][f] = fmaxf(fmaxf(mx0, mx1), fmaxf(mx2, mx3));
        psm[jq][f] = (sm0 + sm1) + (sm2 + sm3);
        __syncthreads();
        if (t < 128) {
            float mx = pmx[0][t], sm = psm[0][t];
#pragma unroll
            for (int q = 1; q < 8; q++) {
                mx = fmaxf(mx, pmx[q][t]);
                sm += psm[q][t];
            }
            if (mode != 2) {
                z[g * 256 + t] += mx;
                z[g * 256 + 128 + t] += sm / (float)k;
            } else {
                zs[t] = z[g * 256 + t] + mx;
                zs[128 + t] = z[g * 256 + 128 + t] + sm / (float)k;
            }
        }
    }

    if (mode == 2) {
        // ---- phase 5: MLP head + log_softmax (fused; z final for this g) ----
        __syncthreads();
        {   // layer 1: 128 outputs x 8 threads
            const int o = t >> 3, oc = t & 7;
            const float* w = &W1[o * 256 + oc * 32];
            const float* zp = &zs[oc * 32];
            float s = 0.f;
#pragma unroll
            for (int i = 0; i < 32; i++) s += w[i] * zp[i];
            s += __shfl_down(s, 4, 8);
            s += __shfl_down(s, 2, 8);
            s += __shfl_down(s, 1, 8);
            if (oc == 0) l1[o] = fmaxf(s + bl1[o], 0.f);
        }
        __syncthreads();
        {   // layer 2: 64 outputs x 16 threads
            const int o = t >> 4, oc = t & 15;
            const float* w = &W2[o * 128 + oc * 8];
            const float* lp = &l1[oc * 8];
            float s = 0.f;
#pragma unroll
            for (int i = 0; i < 8; i++) s += w[i] * lp[i];
            s += __shfl_down(s, 8, 16);
            s += __shfl_down(s, 4, 16);
            s += __shfl_down(s, 2, 16);
            s += __shfl_down(s, 1, 16);
            if (oc == 0) l2[o] = fmaxf(s + bl2[o], 0.f);
        }
        __syncthreads();
        if (t < 64) {
            float pa = W3[t] * l2[t];
            float pb = W3[64 + t] * l2[t];
#pragma unroll
            for (int off = 32; off; off >>= 1) {
                pa += __shfl_down(pa, off, 64);
                pb += __shfl_down(pb, off, 64);
            }
            if (t == 0) {
                float A = pa + bl3[0], B = pb + bl3[1];
                float m = fmaxf(A, B);
                float lse = m + logf(expf(A - m) + expf(B - m));
                outp[g * 2 + 0] = A - lse;
                outp[g * 2 + 1] = B - lse;
            }
        }
        return;
    }
    __syncthreads();

    // ---- phase 4: edge remap + CSR build over pooled node space ----
    for (int e = t; e < EPG; e += 1024) {
        int eg = g * EPG + e;
        int sl, dl, m;
        if (mode == 0) { sl = gsrc[eg] - g * NPER; dl = gdst[eg] - g * NPER; m = 1; }
        else           { int p = epk[eg]; sl = p & 1023; dl = (p >> 10) & 1023; m = p >> 20; }
        int ns = nid[sl], nd = nid[dl];
        int keep = (m && ns >= 0 && nd >= 0) ? 1 : 0;
        epk[eg] = keep ? (ns | (nd << 10) | (1 << 20)) : 0;
        packed[e] = keep ? (ns | (nd << 16)) : -1;
        if (keep) atomicAdd(&cnt[nd], 1);
    }
    __syncthreads();
    if (t < 512) sscan[t] = (t < k) ? cnt[t] : 0;
    __syncthreads();
    for (int d = 1; d < 512; d <<= 1) {
        int v = 0;
        if (t < 512 && t >= d) v = sscan[t - d];
        __syncthreads();
        if (t < 512 && t >= d) sscan[t] += v;
        __syncthreads();
    }
    if (t < k) {
        int excl = (t == 0) ? 0 : sscan[t - 1];
        int st = g * EPG + excl;
        csr_off[g * k + t] = st;
        csr_deg[g * k + t] = cnt[t];
        cur[t] = st;
    }
    __syncthreads();
    for (int e = t; e < EPG; e += 1024) {
        int p = packed[e];
        if (p >= 0) {
            int ns = p & 0xffff, nd = p >> 16;
            int slot = atomicAdd(&cur[nd], 1);
            csr_src[slot] = g * k + ns;
        }
    }
}

// ---------------- launch ----------------
extern "C" void kernel_launch(void* const* d_in, const int* in_sizes, int n_in,
                              void* d_out, int out_size, void* d_ws, size_t ws_size,
                              hipStream_t stream) {
    const float* x        = (const float*)d_in[0];
    const int*   edge_src = (const int*)d_in[1];
    const int*   edge_dst = (const int*)d_in[2];
    const float* Wrel1 = (const float*)d_in[4];
    const float* Wroot1= (const float*)d_in[5];
    const float* b1    = (const float*)d_in[6];
    const float* pw1   = (const float*)d_in[7];
    const float* Wrel2 = (const float*)d_in[8];
    const float* Wroot2= (const float*)d_in[9];
    const float* b2    = (const float*)d_in[10];
    const float* pw2   = (const float*)d_in[11];
    const float* Wrel3 = (const float*)d_in[12];
    const float* Wroot3= (const float*)d_in[13];
    const float* b3    = (const float*)d_in[14];
    const float* pw3   = (const float*)d_in[15];
    const float* W1    = (const float*)d_in[16];
    const float* bl1   = (const float*)d_in[17];
    const float* W2    = (const float*)d_in[18];
    const float* bl2   = (const float*)d_in[19];
    const float* W3    = (const float*)d_in[20];
    const float* bl3   = (const float*)d_in[21];

    char* ws = (char*)d_ws;
    float* t_rel = (float*)(ws + OFF_TREL);
    float* h     = (float*)(ws + OFF_H);
    float* hp    = (float*)(ws + OFF_HP);
    float* sc    = (float*)(ws + OFF_SC);
    int*   epk   = (int*)(ws + OFF_EPK);
    float* z     = (float*)(ws + OFF_Z);
    int*   coff  = (int*)(ws + OFF_COFF);
    int*   cdeg  = (int*)(ws + OFF_CDEG);
    int*   csrc  = (int*)(ws + OFF_CSRC);
    unsigned short* w1h = (unsigned short*)(ws + OFF_W1H);
    unsigned short* w1l = (unsigned short*)(ws + OFF_W1L);
    unsigned short* w2h = (unsigned short*)(ws + OFF_W2H);
    unsigned short* w2l = (unsigned short*)(ws + OFF_W2L);
    unsigned short* w3h = (unsigned short*)(ws + OFF_W3H);
    unsigned short* w3l = (unsigned short*)(ws + OFF_W3L);

    hipMemsetAsync(z, 0, 128ull * 256 * 4, stream);
    prep_w_all<<<dim3(13, 16, 3), 64, 0, stream>>>(
        Wrel1, Wroot1, Wrel2, Wroot2, Wrel3, Wroot3,
        w1h, w1l, w2h, w2l, w3h, w3l);

    // ---------- layer 1 (gemm + fused CSR build in one launch) ----------
    gemm_mfma<13, F_IN, true><<<800 + BATCH, 256, 0, stream>>>(
        x, w1h, w1l, t_rel, h, 800, edge_src, edge_dst, coff, cdeg, csrc);
    agg_score<<<51200 / 8, 256, 0, stream>>>(t_rel, coff, cdeg, csrc, b1, pw1,
                                             h, sc, NPER);
    topk_pool<<<BATCH, 1024, 0, stream>>>(sc, h, hp, z, edge_src, edge_dst,
                                          epk, coff, cdeg, csrc,
                                          NPER, K1, 0,
                                          nullptr, nullptr, nullptr, nullptr,
                                          nullptr, nullptr, nullptr);

    // ---------- layer 2 ----------
    gemm_mfma<4, HD, false><<<640, 256, 0, stream>>>(
        hp, w2h, w2l, t_rel, h, 640, nullptr, nullptr, nullptr, nullptr, nullptr);
    agg_score<<<40960 / 8, 256, 0, stream>>>(t_rel, coff, cdeg, csrc, b2, pw2,
                                             h, sc, K1);
    topk_pool<<<BATCH, 1024, 0, stream>>>(sc, h, hp, z, nullptr, nullptr,
                                          epk, coff, cdeg, csrc,
                                          K1, K2, 1,
                                          nullptr, nullptr, nullptr, nullptr,
                                          nullptr, nullptr, nullptr);

    // ---------- layer 3 (topk fuses the MLP head + log_softmax) ----------
    gemm_mfma<4, HD, false><<<512, 256, 0, stream>>>(
        hp, w3h, w3l, t_rel, h, 512, nullptr, nullptr, nullptr, nullptr, nullptr);
    agg_score<<<32768 / 8, 256, 0, stream>>>(t_rel, coff, cdeg, csrc, b3, pw3,
                                             h, sc, K2);
    topk_pool<<<BATCH, 1024, 0, stream>>>(sc, h, nullptr, z, nullptr, nullptr,
                                          epk, coff, cdeg, csrc,
                                          K2, K3, 2,
                                          W1, bl1, W2, bl2, W3, bl3,
                                          (float*)d_out);
}